// Round 2
// baseline (324.363 us; speedup 1.0000x reference)
//
#include <hip/hip_runtime.h>
#include <hip/hip_bf16.h>
#include <math.h>

typedef __attribute__((ext_vector_type(8))) short short8x;
typedef __attribute__((ext_vector_type(4))) float f32x4;
typedef __attribute__((ext_vector_type(4))) unsigned short u16x4;

#define NSPLIT 16
#define KVROWS 2112

__device__ __forceinline__ unsigned short f2bf(float x) {
  unsigned int u = __float_as_uint(x);
  u += 0x7fffu + ((u >> 16) & 1u);   // RNE
  return (unsigned short)(u >> 16);
}
__device__ __forceinline__ float bf2f(unsigned short u) {
  return __uint_as_float(((unsigned int)u) << 16);
}
__device__ __forceinline__ u16x4 cvt4(float4 v) {
  u16x4 r;
  r[0] = f2bf(v.x); r[1] = f2bf(v.y); r[2] = f2bf(v.z); r[3] = f2bf(v.w);
  return r;
}

// ---------------- K0: build bf16 KV cache [b][n][576] (ckv | rope'd k_pe) -----
__global__ __launch_bounds__(256) void k0_kvprep(
    const float* __restrict__ ckvc, const float* __restrict__ kpec,
    const float* __restrict__ ckvn, const float* __restrict__ kpein,
    const float* __restrict__ cosc, const float* __restrict__ sinc,
    const int* __restrict__ sposp, int cap, unsigned short* __restrict__ kvbf) {
  const int b = blockIdx.y;
  const int n0 = blockIdx.x * 32;
  const int spos = sposp[0];
  if (n0 > spos) return;
  const int tid = threadIdx.x;
  unsigned short* dstb = kvbf + (size_t)b * KVROWS * 576;
  if (n0 + 31 < spos) {  // fast path: all rows from caches
#pragma unroll
    for (int i = 0; i < 18; ++i) {
      int u = tid + i * 256;
      int row = u / 144, c4 = (u - row * 144) * 4;
      int n = n0 + row;
      float4 v;
      if (c4 < 512) v = *(const float4*)(ckvc + ((size_t)b * cap + n) * 512 + c4);
      else          v = *(const float4*)(kpec + ((size_t)b * cap + n) * 64 + (c4 - 512));
      *(u16x4*)(dstb + (size_t)n * 576 + c4) = cvt4(v);
    }
  } else {
    for (int i = 0; i < 18; ++i) {
      int u = tid + i * 256;
      int row = u / 144, c4 = (u - row * 144) * 4;
      int n = n0 + row;
      if (n > spos) continue;
      float4 v;
      if (c4 < 512) {
        v = (n == spos) ? *(const float4*)(ckvn + (size_t)b * 512 + c4)
                        : *(const float4*)(ckvc + ((size_t)b * cap + n) * 512 + c4);
      } else {
        int d = c4 - 512;
        if (n == spos) {
          const float* kp = kpein + b * 64;
          float o[4];
          if (d < 32) {
#pragma unroll
            for (int k = 0; k < 4; ++k) {
              int j = d + k;
              float x0 = kp[2 * j], x1 = kp[2 * j + 1];
              o[k] = x0 * cosc[spos * 64 + j] - x1 * sinc[spos * 64 + j];
            }
          } else {
#pragma unroll
            for (int k = 0; k < 4; ++k) {
              int j = d - 32 + k;
              float x0 = kp[2 * j], x1 = kp[2 * j + 1];
              o[k] = x1 * cosc[spos * 64 + j] + x0 * sinc[spos * 64 + j];
            }
          }
          v = make_float4(o[0], o[1], o[2], o[3]);
        } else {
          v = *(const float4*)(kpec + ((size_t)b * cap + n) * 64 + d);
        }
      }
      *(u16x4*)(dstb + (size_t)n * 576 + c4) = cvt4(v);
    }
  }
}

// ---------------- K1: q_full[b][n] = dot(x[b][:], wq[n][:]) -------------------
__global__ __launch_bounds__(256) void k1_qproj(const float* __restrict__ x,
                                                const float* __restrict__ wq,
                                                float* __restrict__ qfull) {
  __shared__ float xs[16 * 512];
  const int tid = threadIdx.x;
  const int lane = tid & 63, wid = tid >> 6;
  const int row0 = blockIdx.x * 16 + wid * 4;
  float acc[4][16];
#pragma unroll
  for (int r = 0; r < 4; ++r)
#pragma unroll
    for (int bb = 0; bb < 16; ++bb) acc[r][bb] = 0.f;

  for (int kt = 0; kt < 3; ++kt) {
    __syncthreads();
    for (int u = tid; u < 2048; u += 256) {
      int bb = u >> 7, k4 = (u & 127) << 2;
      *(float4*)&xs[bb * 512 + k4] = *(const float4*)&x[bb * 1536 + kt * 512 + k4];
    }
    __syncthreads();
#pragma unroll
    for (int it = 0; it < 2; ++it) {
      const int ko = it * 256 + lane * 4;
      float4 wv[4];
#pragma unroll
      for (int r = 0; r < 4; ++r)
        wv[r] = *(const float4*)&wq[(size_t)(row0 + r) * 1536 + kt * 512 + ko];
#pragma unroll
      for (int bb = 0; bb < 16; ++bb) {
        float4 xv = *(const float4*)&xs[bb * 512 + ko];
#pragma unroll
        for (int r = 0; r < 4; ++r)
          acc[r][bb] += wv[r].x * xv.x + wv[r].y * xv.y + wv[r].z * xv.z + wv[r].w * xv.w;
      }
    }
  }
#pragma unroll
  for (int r = 0; r < 4; ++r)
#pragma unroll
    for (int bb = 0; bb < 16; ++bb) {
      float v = acc[r][bb];
#pragma unroll
      for (int mk = 1; mk < 64; mk <<= 1) v += __shfl_xor(v, mk, 64);
      acc[r][bb] = v;
    }
#pragma unroll
  for (int r = 0; r < 4; ++r) {
    const int row = row0 + r;
#pragma unroll
    for (int bb = 0; bb < 16; ++bb)
      if (lane == bb) qfull[bb * 24576 + row] = acc[r][bb];
  }
}

// ---------------- K2: rope q_pe -> qcat[bh][512..575] bf16 --------------------
__global__ void k2_rope(const float* __restrict__ qfull,
                        const float* __restrict__ cosc, const float* __restrict__ sinc,
                        const int* __restrict__ sposp, unsigned short* __restrict__ qcat) {
  const int j = threadIdx.x;  // 0..31
  const int h = blockIdx.x;
  const int b = blockIdx.y;
  const int pos = sposp[0];
  const float cj = cosc[pos * 64 + j];
  const float sj = sinc[pos * 64 + j];
  const float* src = qfull + b * 24576 + h * 192 + 128;
  float x0 = src[2 * j], x1 = src[2 * j + 1];
  unsigned short* dst = qcat + (size_t)(b * 128 + h) * 576 + 512;
  dst[j] = f2bf(x0 * cj - x1 * sj);
  dst[j + 32] = f2bf(x1 * cj + x0 * sj);
}

// ---------------- K3: absorb -> qcat[bh][0..511] bf16 -------------------------
__global__ __launch_bounds__(256) void k3_absorb(const float* __restrict__ qfull,
                                                 const float* __restrict__ wkv,
                                                 unsigned short* __restrict__ qcat) {
  __shared__ float qs[16 * 128];
  const int tid = threadIdx.x;
  const int h = blockIdx.x;
  const int half = blockIdx.y;
  for (int u = tid; u < 2048; u += 256) {
    int bb = u >> 7, d = u & 127;
    qs[u] = qfull[bb * 24576 + h * 192 + d];
  }
  __syncthreads();
  const int c = half * 256 + tid;
  float acc[16];
#pragma unroll
  for (int bb = 0; bb < 16; ++bb) acc[bb] = 0.f;
  const float* wbase = wkv + (size_t)h * 256 * 512;
  for (int d = 0; d < 128; ++d) {
    const float w = wbase[d * 512 + c];
#pragma unroll
    for (int bb = 0; bb < 16; ++bb) acc[bb] += qs[bb * 128 + d] * w;
  }
#pragma unroll
  for (int bb = 0; bb < 16; ++bb)
    qcat[(size_t)(bb * 128 + h) * 576 + c] = f2bf(acc[bb]);
}

// ---------------- K4: flash decode (bf16 MFMA, swizzled LDS) ------------------
// grid (NSPLIT, 2, 16); block 256 = 4 waves x 16 heads; 2 blocks/CU
__global__ __launch_bounds__(256, 2) void k4_attn(
    const unsigned short* __restrict__ kvbf, const unsigned short* __restrict__ qcat,
    const int* __restrict__ sposp,
    unsigned short* __restrict__ opart, float* __restrict__ mlp) {
  __shared__ __align__(16) unsigned short kv_sh[32 * 576];  // [n][k] chunk-XOR swz
  __shared__ __align__(16) unsigned short v2_sh[512 * 32];  // [c][n] chunk-XOR swz
  __shared__ __align__(16) unsigned short p_sh[4 * 16 * 40];

  const int tid = threadIdx.x;
  const int split = blockIdx.x, hg = blockIdx.y, b = blockIdx.z;
  const int spos = sposp[0];
  const int kvlen = spos + 1;
  const int L = (((kvlen + NSPLIT - 1) / NSPLIT) + 31) & ~31;
  const int lo = split * L;
  const int hi = min(lo + L, kvlen);
  const int nt = (hi > lo) ? ((hi - lo + 31) >> 5) : 0;

  const int lane = tid & 63, wid = tid >> 6;
  const int l15 = lane & 15, lg = lane >> 4;
  const int x0 = l15 & 7;

  // Q fragments in registers (16 heads per wave)
  const int hrow = b * 128 + hg * 64 + wid * 16 + l15;
  const unsigned short* qrow = qcat + (size_t)hrow * 576;
  short8x qf[18];
#pragma unroll
  for (int s = 0; s < 18; ++s)
    qf[s] = *(const short8x*)(qrow + s * 32 + lg * 8);

  f32x4 acc[32];
#pragma unroll
  for (int i = 0; i < 32; ++i) acc[i] = (f32x4){0.f, 0.f, 0.f, 0.f};
  float mold[4] = {-1e30f, -1e30f, -1e30f, -1e30f};
  float lsum[4] = {0.f, 0.f, 0.f, 0.f};
  const float C2 = (1.0f / sqrtf(192.0f)) * 1.4426950408889634f;

  const int vBase = l15 * 32 + ((lg ^ ((l15 >> 1) & 3)) << 3);
  const int pWbase = wid * 640;

  const unsigned short* srcb = kvbf + (size_t)b * KVROWS * 576;

  for (int t = 0; t < nt; ++t) {
    const int n0 = lo + t * 32;
    const unsigned short* src = srcb + (size_t)n0 * 576;
    // stage KV tile: 9 coalesced 16B chunks per thread, chunk-XOR into LDS
#pragma unroll
    for (int i = 0; i < 9; ++i) {
      int u = tid + i * 256;          // chunk id 0..2303
      int row = u / 72, cc = u - row * 72;
      f32x4 vv = *(const f32x4*)(src + row * 576 + cc * 8);
      *(f32x4*)&kv_sh[row * 576 + ((cc * 8) ^ ((row & 7) << 3))] = vv;
    }
    __syncthreads();

    // build V^T [c][n] from kv_sh (LDS->LDS)
#pragma unroll
    for (int i = 0; i < 16; ++i) {
      int idx = tid + i * 256;        // 0..4095
      int c = idx & 511, ng = idx >> 9;  // ng: n-group of 4
      u16x4 w;
#pragma unroll
      for (int k = 0; k < 4; ++k) {
        int n = ng * 4 + k;
        w[k] = kv_sh[n * 576 + (c ^ ((n & 7) << 3))];
      }
      *(u16x4*)&v2_sh[c * 32 + (((ng >> 1) ^ ((c >> 1) & 3)) << 3) + (ng & 1) * 4] = w;
    }

    // QK^T
    f32x4 D0 = (f32x4){0.f, 0.f, 0.f, 0.f};
    f32x4 D1 = (f32x4){0.f, 0.f, 0.f, 0.f};
#pragma unroll
    for (int s = 0; s < 18; ++s) {
      short8x fb0 = *(const short8x*)&kv_sh[l15 * 576 + ((s * 32 + lg * 8) ^ (x0 << 3))];
      short8x fb1 = *(const short8x*)&kv_sh[(16 + l15) * 576 + ((s * 32 + lg * 8) ^ (x0 << 3))];
      D0 = __builtin_amdgcn_mfma_f32_16x16x32_bf16(qf[s], fb0, D0, 0, 0, 0);
      D1 = __builtin_amdgcn_mfma_f32_16x16x32_bf16(qf[s], fb1, D1, 0, 0, 0);
    }

    // online softmax
    const bool v0 = (n0 + l15) < hi;
    const bool v1 = (n0 + 16 + l15) < hi;
    float alpha[4];
#pragma unroll
    for (int r = 0; r < 4; ++r) {
      const float t0 = v0 ? D0[r] * C2 : -1e30f;
      const float t1 = v1 ? D1[r] * C2 : -1e30f;
      float mx = fmaxf(t0, t1);
      mx = fmaxf(mx, __shfl_xor(mx, 1, 64));
      mx = fmaxf(mx, __shfl_xor(mx, 2, 64));
      mx = fmaxf(mx, __shfl_xor(mx, 4, 64));
      mx = fmaxf(mx, __shfl_xor(mx, 8, 64));
      const float mn = fmaxf(mold[r], mx);
      alpha[r] = exp2f(mold[r] - mn);
      const float p0 = v0 ? exp2f(t0 - mn) : 0.f;
      const float p1 = v1 ? exp2f(t1 - mn) : 0.f;
      float rs = p0 + p1;
      rs += __shfl_xor(rs, 1, 64);
      rs += __shfl_xor(rs, 2, 64);
      rs += __shfl_xor(rs, 4, 64);
      rs += __shfl_xor(rs, 8, 64);
      lsum[r] = lsum[r] * alpha[r] + rs;
      mold[r] = mn;
      p_sh[pWbase + (lg * 4 + r) * 40 + l15] = f2bf(p0);
      p_sh[pWbase + (lg * 4 + r) * 40 + 16 + l15] = f2bf(p1);
    }
    const f32x4 av = {alpha[0], alpha[1], alpha[2], alpha[3]};
#pragma unroll
    for (int cg = 0; cg < 32; ++cg) acc[cg] *= av;

    __syncthreads();  // v2_sh ready (p_sh is own-wave)

    const short8x pa = *(const short8x*)&p_sh[pWbase + l15 * 40 + lg * 8];
#pragma unroll
    for (int cg = 0; cg < 32; ++cg) {
      short8x bv = *(const short8x*)&v2_sh[cg * 512 + vBase];
      acc[cg] = __builtin_amdgcn_mfma_f32_16x16x32_bf16(pa, bv, acc[cg], 0, 0, 0);
    }
    // no third sync needed: next kv_sh write races only with PV (reads v2/p only)
  }

  // epilogue
  const int hb = b * 128 + hg * 64 + wid * 16 + lg * 4;
#pragma unroll
  for (int r = 0; r < 4; ++r) {
    const size_t ob = ((size_t)(hb + r) * NSPLIT + split) * 512;
#pragma unroll
    for (int cg = 0; cg < 32; ++cg)
      opart[ob + cg * 16 + l15] = f2bf(acc[cg][r]);
    if (l15 == 0) {
      mlp[(size_t)(hb + r) * (2 * NSPLIT) + split * 2] = mold[r];
      mlp[(size_t)(hb + r) * (2 * NSPLIT) + split * 2 + 1] = lsum[r];
    }
  }
}

// ---------------- K5: combine splits ------------------------------------------
__global__ __launch_bounds__(256) void k5_combine(const unsigned short* __restrict__ opart,
                                                  const float* __restrict__ mlp,
                                                  float* __restrict__ ofin) {
  const int gid = blockIdx.x * 256 + threadIdx.x;
  const int bh = gid >> 9, c = gid & 511;
  const float* m = mlp + (size_t)bh * (2 * NSPLIT);
  float mi[NSPLIT], li[NSPLIT];
  float M = -1e30f;
#pragma unroll
  for (int i = 0; i < NSPLIT; ++i) {
    mi[i] = m[i * 2];
    li[i] = m[i * 2 + 1];
    M = fmaxf(M, mi[i]);
  }
  float Ls = 0.f, o = 0.f;
#pragma unroll
  for (int i = 0; i < NSPLIT; ++i) {
    const float w = exp2f(mi[i] - M);
    Ls += li[i] * w;
    o += w * bf2f(opart[((size_t)bh * NSPLIT + i) * 512 + c]);
  }
  ofin[gid] = o / Ls;
}

// ---------------- K6: out[b][h][d] = sum_c O[b][h][c] * wkv[h][128+d][c] ------
__global__ __launch_bounds__(256) void k6_proj(const float* __restrict__ ofin,
                                               const float* __restrict__ wkv,
                                               float* __restrict__ out) {
  __shared__ float os[16 * 512];
  const int tid = threadIdx.x;
  const int dh = blockIdx.x;
  const int h = blockIdx.y;
  for (int u = tid; u < 8192; u += 256) {
    int bb = u >> 9, c = u & 511;
    os[u] = ofin[(size_t)(bb * 128 + h) * 512 + c];
  }
  __syncthreads();
  const int q = tid >> 2, cq = tid & 3;
  const int d = dh * 64 + q;
  const float* wrow = wkv + ((size_t)(h * 256 + 128 + d)) * 512;
  float acc[16];
#pragma unroll
  for (int bb = 0; bb < 16; ++bb) acc[bb] = 0.f;
  for (int i = 0; i < 32; ++i) {
    const int c = cq * 4 + i * 16;
    const float4 w4 = *(const float4*)&wrow[c];
#pragma unroll
    for (int bb = 0; bb < 16; ++bb) {
      const float4 o4 = *(const float4*)&os[bb * 512 + c];
      acc[bb] += w4.x * o4.x + w4.y * o4.y + w4.z * o4.z + w4.w * o4.w;
    }
  }
#pragma unroll
  for (int bb = 0; bb < 16; ++bb) {
    float v = acc[bb];
    v += __shfl_xor(v, 1, 64);
    v += __shfl_xor(v, 2, 64);
    if (cq == 0) out[(size_t)(bb * 128 + h) * 128 + d] = v;
  }
}

extern "C" void kernel_launch(void* const* d_in, const int* in_sizes, int n_in,
                              void* d_out, int out_size, void* d_ws, size_t ws_size,
                              hipStream_t stream) {
  const float* x = (const float*)d_in[0];
  const float* ckvn = (const float*)d_in[1];
  const float* kpein = (const float*)d_in[2];
  const int* sposp = (const int*)d_in[4];
  const float* ckvc = (const float*)d_in[5];
  const float* kpec = (const float*)d_in[6];
  const float* sinc = (const float*)d_in[7];
  const float* cosc = (const float*)d_in[8];
  const float* wkv = (const float*)d_in[9];
  const float* wq = (const float*)d_in[10];
  float* out = (float*)d_out;

  const int cap = in_sizes[5] / (16 * 512);

  float* ws = (float*)d_ws;
  float* qfull = ws;                                        // 393,216 f
  float* ofin = ws + 393216;                                // 1,048,576 f
  float* mlp = ws + 1441792;                                // 65,536 f
  unsigned short* qcat = (unsigned short*)(ws + 1507328);   // 1,179,648 us
  unsigned short* kvbf = (unsigned short*)(ws + 2097152);   // 19,464,192 us
  unsigned short* opart = (unsigned short*)(ws + 11829248); // 16,777,216 us
  // total 20,217,856 floats = 80.9 MB

  k0_kvprep<<<dim3(KVROWS / 32, 16), 256, 0, stream>>>(ckvc, kpec, ckvn, kpein,
                                                       cosc, sinc, sposp, cap, kvbf);
  k1_qproj<<<dim3(1536), 256, 0, stream>>>(x, wq, qfull);
  k2_rope<<<dim3(128, 16), 32, 0, stream>>>(qfull, cosc, sinc, sposp, qcat);
  k3_absorb<<<dim3(128, 2), 256, 0, stream>>>(qfull, wkv, qcat);
  k4_attn<<<dim3(NSPLIT, 2, 16), 256, 0, stream>>>(kvbf, qcat, sposp, opart, mlp);
  k5_combine<<<dim3(4096), 256, 0, stream>>>(opart, mlp, ofin);
  k6_proj<<<dim3(2, 128), 256, 0, stream>>>(ofin, wkv, out);
}

// Round 3
// 249.949 us; speedup vs baseline: 1.2977x; 1.2977x over previous
//
#include <hip/hip_runtime.h>
#include <hip/hip_bf16.h>
#include <math.h>

typedef __attribute__((ext_vector_type(8))) short short8x;
typedef __attribute__((ext_vector_type(4))) float f32x4;
typedef __attribute__((ext_vector_type(4))) unsigned short u16x4;

#define NSPLIT 16
#define NTILE 66
#define KVROWS (NTILE * 32)

__device__ __forceinline__ unsigned short f2bf(float x) {
  unsigned int u = __float_as_uint(x);
  u += 0x7fffu + ((u >> 16) & 1u);   // RNE
  return (unsigned short)(u >> 16);
}
__device__ __forceinline__ float bf2f(unsigned short u) {
  return __uint_as_float(((unsigned int)u) << 16);
}
__device__ __forceinline__ u16x4 cvt4(float4 v) {
  u16x4 r;
  r[0] = f2bf(v.x); r[1] = f2bf(v.y); r[2] = f2bf(v.z); r[3] = f2bf(v.w);
  return r;
}
__device__ __forceinline__ void gload_lds16(const unsigned short* g, unsigned short* l) {
  __builtin_amdgcn_global_load_lds(
      (const __attribute__((address_space(1))) unsigned int*)(const void*)g,
      (__attribute__((address_space(3))) unsigned int*)(void*)l, 16, 0, 0);
}

// ---------------- K0: bf16 KV cache in 2 layouts + zero tail ------------------
// kvbf[b][n][576] row-major ; vT[b][tile][c:512][n:32] (n-fast)
__global__ __launch_bounds__(256) void k0_kvprep(
    const float* __restrict__ ckvc, const float* __restrict__ kpec,
    const float* __restrict__ ckvn, const float* __restrict__ kpein,
    const float* __restrict__ cosc, const float* __restrict__ sinc,
    const int* __restrict__ sposp, int cap,
    unsigned short* __restrict__ kvbf, unsigned short* __restrict__ vT) {
  __shared__ __align__(16) unsigned short tile_sh[32 * 576];
  const int b = blockIdx.y;
  const int tile = blockIdx.x;
  const int n0 = tile * 32;
  const int spos = sposp[0];
  const int tid = threadIdx.x;
#pragma unroll
  for (int i = 0; i < 18; ++i) {
    int u = tid + i * 256;
    int row = u / 144, c4 = (u - row * 144) * 4;
    int n = n0 + row;
    float4 v = make_float4(0.f, 0.f, 0.f, 0.f);
    if (n < spos) {
      if (c4 < 512) v = *(const float4*)(ckvc + ((size_t)b * cap + n) * 512 + c4);
      else          v = *(const float4*)(kpec + ((size_t)b * cap + n) * 64 + (c4 - 512));
    } else if (n == spos) {
      if (c4 < 512) v = *(const float4*)(ckvn + (size_t)b * 512 + c4);
      else {
        int d = c4 - 512;
        const float* kp = kpein + b * 64;
        float o[4];
        if (d < 32) {
#pragma unroll
          for (int k = 0; k < 4; ++k) {
            int j = d + k;
            o[k] = kp[2 * j] * cosc[spos * 64 + j] - kp[2 * j + 1] * sinc[spos * 64 + j];
          }
        } else {
#pragma unroll
          for (int k = 0; k < 4; ++k) {
            int j = d - 32 + k;
            o[k] = kp[2 * j + 1] * cosc[spos * 64 + j] + kp[2 * j] * sinc[spos * 64 + j];
          }
        }
        v = make_float4(o[0], o[1], o[2], o[3]);
      }
    }
    *(u16x4*)&tile_sh[row * 576 + c4] = cvt4(v);
  }
  __syncthreads();
  // (a) row-major copy out
  unsigned short* dst = kvbf + ((size_t)b * KVROWS + n0) * 576;
#pragma unroll
  for (int i = 0; i < 9; ++i) {
    int u = tid + i * 256;  // 16B chunk, 2304 total
    *(f32x4*)&dst[u * 8] = *(const f32x4*)&tile_sh[u * 8];
  }
  // (b) n-fast transposed V
  unsigned short* vdst = vT + ((size_t)b * NTILE + tile) * 16384;
#pragma unroll
  for (int i = 0; i < 16; ++i) {
    int u = tid + i * 256;
    int c = u & 511, ng = u >> 9;
    u16x4 w;
#pragma unroll
    for (int k = 0; k < 4; ++k) w[k] = tile_sh[(ng * 4 + k) * 576 + c];
    *(u16x4*)&vdst[c * 32 + ng * 4] = w;
  }
}

// ---------------- K1: q_full[b][n] = dot(x[b][:], wq[n][:]) -------------------
__global__ __launch_bounds__(256) void k1_qproj(const float* __restrict__ x,
                                                const float* __restrict__ wq,
                                                float* __restrict__ qfull) {
  __shared__ float xs[16 * 512];
  const int tid = threadIdx.x;
  const int lane = tid & 63, wid = tid >> 6;
  const int row0 = blockIdx.x * 16 + wid * 4;
  float acc[4][16];
#pragma unroll
  for (int r = 0; r < 4; ++r)
#pragma unroll
    for (int bb = 0; bb < 16; ++bb) acc[r][bb] = 0.f;

  for (int kt = 0; kt < 3; ++kt) {
    __syncthreads();
    for (int u = tid; u < 2048; u += 256) {
      int bb = u >> 7, k4 = (u & 127) << 2;
      *(float4*)&xs[bb * 512 + k4] = *(const float4*)&x[bb * 1536 + kt * 512 + k4];
    }
    __syncthreads();
#pragma unroll
    for (int it = 0; it < 2; ++it) {
      const int ko = it * 256 + lane * 4;
      float4 wv[4];
#pragma unroll
      for (int r = 0; r < 4; ++r)
        wv[r] = *(const float4*)&wq[(size_t)(row0 + r) * 1536 + kt * 512 + ko];
#pragma unroll
      for (int bb = 0; bb < 16; ++bb) {
        float4 xv = *(const float4*)&xs[bb * 512 + ko];
#pragma unroll
        for (int r = 0; r < 4; ++r)
          acc[r][bb] += wv[r].x * xv.x + wv[r].y * xv.y + wv[r].z * xv.z + wv[r].w * xv.w;
      }
    }
  }
#pragma unroll
  for (int r = 0; r < 4; ++r)
#pragma unroll
    for (int bb = 0; bb < 16; ++bb) {
      float v = acc[r][bb];
#pragma unroll
      for (int mk = 1; mk < 64; mk <<= 1) v += __shfl_xor(v, mk, 64);
      acc[r][bb] = v;
    }
#pragma unroll
  for (int r = 0; r < 4; ++r) {
    const int row = row0 + r;
#pragma unroll
    for (int bb = 0; bb < 16; ++bb)
      if (lane == bb) qfull[bb * 24576 + row] = acc[r][bb];
  }
}

// ---------------- K2: rope q_pe -> qcat[bh][512..575] bf16 --------------------
__global__ void k2_rope(const float* __restrict__ qfull,
                        const float* __restrict__ cosc, const float* __restrict__ sinc,
                        const int* __restrict__ sposp, unsigned short* __restrict__ qcat) {
  const int j = threadIdx.x;  // 0..31
  const int h = blockIdx.x;
  const int b = blockIdx.y;
  const int pos = sposp[0];
  const float cj = cosc[pos * 64 + j];
  const float sj = sinc[pos * 64 + j];
  const float* src = qfull + b * 24576 + h * 192 + 128;
  float x0 = src[2 * j], x1 = src[2 * j + 1];
  unsigned short* dst = qcat + (size_t)(b * 128 + h) * 576 + 512;
  dst[j] = f2bf(x0 * cj - x1 * sj);
  dst[j + 32] = f2bf(x1 * cj + x0 * sj);
}

// ---------------- K3: absorb -> qcat[bh][0..511] bf16 -------------------------
__global__ __launch_bounds__(256) void k3_absorb(const float* __restrict__ qfull,
                                                 const float* __restrict__ wkv,
                                                 unsigned short* __restrict__ qcat) {
  __shared__ float qs[16 * 128];
  const int tid = threadIdx.x;
  const int h = blockIdx.x;
  const int half = blockIdx.y;
  for (int u = tid; u < 2048; u += 256) {
    int bb = u >> 7, d = u & 127;
    qs[u] = qfull[bb * 24576 + h * 192 + d];
  }
  __syncthreads();
  const int c = half * 256 + tid;
  float acc[16];
#pragma unroll
  for (int bb = 0; bb < 16; ++bb) acc[bb] = 0.f;
  const float* wbase = wkv + (size_t)h * 256 * 512;
  for (int d = 0; d < 128; ++d) {
    const float w = wbase[d * 512 + c];
#pragma unroll
    for (int bb = 0; bb < 16; ++bb) acc[bb] += qs[bb * 128 + d] * w;
  }
#pragma unroll
  for (int bb = 0; bb < 16; ++bb)
    qcat[(size_t)(bb * 128 + h) * 576 + c] = f2bf(acc[bb]);
}

// ---------------- K4: flash decode, 8 waves = 128 heads, dbuf global_load_lds -
// grid (NSPLIT, 16); block 512; 1 block/CU (149.5 KB LDS)
__global__ __launch_bounds__(512, 2) void k4_attn(
    const unsigned short* __restrict__ kvbf, const unsigned short* __restrict__ vT,
    const unsigned short* __restrict__ qcat, const int* __restrict__ sposp,
    unsigned short* __restrict__ opart, float* __restrict__ mlp) {
  __shared__ __align__(16) unsigned short kv_sh[2][32 * 576];  // linear; src pre-swz
  __shared__ __align__(16) unsigned short vt_sh[2][512 * 32];  // linear
  __shared__ __align__(16) unsigned short p_sh[8 * 640];       // wave-private

  const int tid = threadIdx.x;
  const int split = blockIdx.x, b = blockIdx.y;
  const int kvlen = sposp[0] + 1;
  const int lane = tid & 63, wid = tid >> 6;
  const int l15 = lane & 15, lg = lane >> 4;

  const unsigned short* kvb = kvbf + (size_t)b * KVROWS * 576;
  const unsigned short* vtb = vT + (size_t)b * NTILE * 16384;

  // Q fragments in registers (16 heads per wave; 8 waves = 128 heads)
  const int hrow = b * 128 + wid * 16 + l15;
  const unsigned short* qrow = qcat + (size_t)hrow * 576;
  short8x qf[18];
#pragma unroll
  for (int s = 0; s < 18; ++s)
    qf[s] = *(const short8x*)(qrow + s * 32 + lg * 8);

  f32x4 acc[32];
#pragma unroll
  for (int i = 0; i < 32; ++i) acc[i] = (f32x4){0.f, 0.f, 0.f, 0.f};
  float mold[4] = {-1e30f, -1e30f, -1e30f, -1e30f};
  float lsum[4] = {0.f, 0.f, 0.f, 0.f};
  const float C2 = (1.0f / sqrtf(192.0f)) * 1.4426950408889634f;

  auto STAGE = [&](int pb, int tt) {
    const unsigned short* ksrc = kvb + (size_t)tt * 32 * 576;
    for (int j = wid; j < 36; j += 8) {           // 2304 kv chunks
      int u = j * 64 + lane;
      int row = u / 72, cc = u - row * 72;
      gload_lds16(ksrc + row * 576 + ((cc ^ (row & 7)) * 8), &kv_sh[pb][j * 512]);
    }
    const unsigned short* vsrc = vtb + (size_t)tt * 16384;
    for (int j = wid; j < 32; j += 8)             // 2048 vT chunks, linear
      gload_lds16(vsrc + j * 512 + lane * 8, &vt_sh[pb][j * 512]);
  };

  if (split * 32 < kvlen) STAGE(0, split);
  int pb = 0;
  for (int tt = split; tt * 32 < kvlen; tt += NSPLIT, pb ^= 1) {
    __syncthreads();   // drains this tile's async loads; others' via barrier
    if ((tt + NSPLIT) * 32 < kvlen) STAGE(pb ^ 1, tt + NSPLIT);
    const int n0 = tt * 32;

    // QK^T : swizzled reads (LDS[n][c8] holds global chunk c8^(n&7))
    f32x4 D0 = (f32x4){0.f, 0.f, 0.f, 0.f};
    f32x4 D1 = (f32x4){0.f, 0.f, 0.f, 0.f};
#pragma unroll
    for (int s = 0; s < 18; ++s) {
      const int c8 = (s * 4 + lg) ^ (l15 & 7);
      short8x fb0 = *(const short8x*)&kv_sh[pb][l15 * 576 + c8 * 8];
      short8x fb1 = *(const short8x*)&kv_sh[pb][(16 + l15) * 576 + c8 * 8];
      D0 = __builtin_amdgcn_mfma_f32_16x16x32_bf16(qf[s], fb0, D0, 0, 0, 0);
      D1 = __builtin_amdgcn_mfma_f32_16x16x32_bf16(qf[s], fb1, D1, 0, 0, 0);
    }

    // online softmax (per-wave, 16 heads)
    const bool v0 = (n0 + l15) < kvlen;
    const bool v1 = (n0 + 16 + l15) < kvlen;
    float alpha[4];
#pragma unroll
    for (int r = 0; r < 4; ++r) {
      const float t0 = v0 ? D0[r] * C2 : -1e30f;
      const float t1 = v1 ? D1[r] * C2 : -1e30f;
      float mx = fmaxf(t0, t1);
      mx = fmaxf(mx, __shfl_xor(mx, 1, 64));
      mx = fmaxf(mx, __shfl_xor(mx, 2, 64));
      mx = fmaxf(mx, __shfl_xor(mx, 4, 64));
      mx = fmaxf(mx, __shfl_xor(mx, 8, 64));
      const float mn = fmaxf(mold[r], mx);
      alpha[r] = exp2f(mold[r] - mn);
      const float p0 = v0 ? exp2f(t0 - mn) : 0.f;
      const float p1 = v1 ? exp2f(t1 - mn) : 0.f;
      float rs = p0 + p1;
      rs += __shfl_xor(rs, 1, 64);
      rs += __shfl_xor(rs, 2, 64);
      rs += __shfl_xor(rs, 4, 64);
      rs += __shfl_xor(rs, 8, 64);
      lsum[r] = lsum[r] * alpha[r] + rs;
      mold[r] = mn;
      p_sh[wid * 640 + (lg * 4 + r) * 40 + l15] = f2bf(p0);
      p_sh[wid * 640 + (lg * 4 + r) * 40 + 16 + l15] = f2bf(p1);
    }
    const f32x4 av = {alpha[0], alpha[1], alpha[2], alpha[3]};
#pragma unroll
    for (int cg = 0; cg < 32; ++cg) acc[cg] *= av;

    // PV (wave-private p_sh; vt_sh staged at this tile's sync)
    const short8x pa = *(const short8x*)&p_sh[wid * 640 + l15 * 40 + lg * 8];
#pragma unroll
    for (int cg = 0; cg < 32; ++cg) {
      short8x bv = *(const short8x*)&vt_sh[pb][cg * 512 + l15 * 32 + lg * 8];
      acc[cg] = __builtin_amdgcn_mfma_f32_16x16x32_bf16(pa, bv, acc[cg], 0, 0, 0);
    }
  }

  // epilogue
  const int hb = b * 128 + wid * 16 + lg * 4;
#pragma unroll
  for (int r = 0; r < 4; ++r) {
    const size_t ob = ((size_t)(hb + r) * NSPLIT + split) * 512;
#pragma unroll
    for (int cg = 0; cg < 32; ++cg)
      opart[ob + cg * 16 + l15] = f2bf(acc[cg][r]);
    if (l15 == 0) {
      mlp[(size_t)(hb + r) * (2 * NSPLIT) + split * 2] = mold[r];
      mlp[(size_t)(hb + r) * (2 * NSPLIT) + split * 2 + 1] = lsum[r];
    }
  }
}

// ---------------- K5: combine splits ------------------------------------------
__global__ __launch_bounds__(256) void k5_combine(const unsigned short* __restrict__ opart,
                                                  const float* __restrict__ mlp,
                                                  float* __restrict__ ofin) {
  const int gid = blockIdx.x * 256 + threadIdx.x;
  const int bh = gid >> 9, c = gid & 511;
  const float* m = mlp + (size_t)bh * (2 * NSPLIT);
  float mi[NSPLIT], li[NSPLIT];
  float M = -1e30f;
#pragma unroll
  for (int i = 0; i < NSPLIT; ++i) {
    mi[i] = m[i * 2];
    li[i] = m[i * 2 + 1];
    M = fmaxf(M, mi[i]);
  }
  float Ls = 0.f, o = 0.f;
#pragma unroll
  for (int i = 0; i < NSPLIT; ++i) {
    const float w = exp2f(mi[i] - M);
    Ls += li[i] * w;
    o += w * bf2f(opart[((size_t)bh * NSPLIT + i) * 512 + c]);
  }
  ofin[gid] = o / Ls;
}

// ---------------- K6: out[b][h][d] = sum_c O[b][h][c] * wkv[h][128+d][c] ------
__global__ __launch_bounds__(256) void k6_proj(const float* __restrict__ ofin,
                                               const float* __restrict__ wkv,
                                               float* __restrict__ out) {
  __shared__ float os[16 * 512];
  const int tid = threadIdx.x;
  const int dh = blockIdx.x;
  const int h = blockIdx.y;
  for (int u = tid; u < 8192; u += 256) {
    int bb = u >> 9, c = u & 511;
    os[u] = ofin[(size_t)(bb * 128 + h) * 512 + c];
  }
  __syncthreads();
  const int q = tid >> 2, cq = tid & 3;
  const int d = dh * 64 + q;
  const float* wrow = wkv + ((size_t)(h * 256 + 128 + d)) * 512;
  float acc[16];
#pragma unroll
  for (int bb = 0; bb < 16; ++bb) acc[bb] = 0.f;
  for (int i = 0; i < 32; ++i) {
    const int c = cq * 4 + i * 16;
    const float4 w4 = *(const float4*)&wrow[c];
#pragma unroll
    for (int bb = 0; bb < 16; ++bb) {
      const float4 o4 = *(const float4*)&os[bb * 512 + c];
      acc[bb] += w4.x * o4.x + w4.y * o4.y + w4.z * o4.z + w4.w * o4.w;
    }
  }
#pragma unroll
  for (int bb = 0; bb < 16; ++bb) {
    float v = acc[bb];
    v += __shfl_xor(v, 1, 64);
    v += __shfl_xor(v, 2, 64);
    if (cq == 0) out[(size_t)(bb * 128 + h) * 128 + d] = v;
  }
}

extern "C" void kernel_launch(void* const* d_in, const int* in_sizes, int n_in,
                              void* d_out, int out_size, void* d_ws, size_t ws_size,
                              hipStream_t stream) {
  const float* x = (const float*)d_in[0];
  const float* ckvn = (const float*)d_in[1];
  const float* kpein = (const float*)d_in[2];
  const int* sposp = (const int*)d_in[4];
  const float* ckvc = (const float*)d_in[5];
  const float* kpec = (const float*)d_in[6];
  const float* sinc = (const float*)d_in[7];
  const float* cosc = (const float*)d_in[8];
  const float* wkv = (const float*)d_in[9];
  const float* wq = (const float*)d_in[10];
  float* out = (float*)d_out;

  const int cap = in_sizes[5] / (16 * 512);

  float* ws = (float*)d_ws;
  float* qfull = ws;                                        // 393,216 f
  float* ofin = ws + 393216;                                // 1,048,576 f
  float* mlp = ws + 1441792;                                // 65,536 f
  unsigned short* qcat = (unsigned short*)(ws + 1507328);   // 1,179,648 us
  unsigned short* kvbf = (unsigned short*)(ws + 2097152);   // 19,464,192 us
  unsigned short* vT   = (unsigned short*)(ws + 11829248);  // 17,301,504 us
  unsigned short* opart = (unsigned short*)(ws + 20480000); // 16,777,216 us
  // total 28,868,608 f = 115.5 MB

  k0_kvprep<<<dim3(NTILE, 16), 256, 0, stream>>>(ckvc, kpec, ckvn, kpein,
                                                 cosc, sinc, sposp, cap, kvbf, vT);
  k1_qproj<<<dim3(1536), 256, 0, stream>>>(x, wq, qfull);
  k2_rope<<<dim3(128, 16), 32, 0, stream>>>(qfull, cosc, sinc, sposp, qcat);
  k3_absorb<<<dim3(128, 2), 256, 0, stream>>>(qfull, wkv, qcat);
  k4_attn<<<dim3(NSPLIT, 16), 512, 0, stream>>>(kvbf, vT, qcat, sposp, opart, mlp);
  k5_combine<<<dim3(4096), 256, 0, stream>>>(opart, mlp, ofin);
  k6_proj<<<dim3(2, 128), 256, 0, stream>>>(ofin, wkv, out);
}

// Round 4
// 208.826 us; speedup vs baseline: 1.5533x; 1.1969x over previous
//
#include <hip/hip_runtime.h>
#include <hip/hip_bf16.h>
#include <math.h>

typedef __attribute__((ext_vector_type(8))) short short8x;
typedef __attribute__((ext_vector_type(4))) float f32x4;
typedef __attribute__((ext_vector_type(4))) unsigned short u16x4;

#define NSPLIT 16
#define NTILE 66
#define KVROWS (NTILE * 32)

__device__ __forceinline__ unsigned short f2bf(float x) {
  unsigned int u = __float_as_uint(x);
  u += 0x7fffu + ((u >> 16) & 1u);   // RNE
  return (unsigned short)(u >> 16);
}
__device__ __forceinline__ float bf2f(unsigned short u) {
  return __uint_as_float(((unsigned int)u) << 16);
}
__device__ __forceinline__ u16x4 cvt4(float4 v) {
  u16x4 r;
  r[0] = f2bf(v.x); r[1] = f2bf(v.y); r[2] = f2bf(v.z); r[3] = f2bf(v.w);
  return r;
}
__device__ __forceinline__ void gload_lds16(const unsigned short* g, unsigned short* l) {
  __builtin_amdgcn_global_load_lds(
      (const __attribute__((address_space(1))) unsigned int*)(const void*)g,
      (__attribute__((address_space(3))) unsigned int*)(void*)l, 16, 0, 0);
}

// ================= kA: fused k0 (KV prep, blocks 0..1055) || k1 (q-proj) ======
__global__ __launch_bounds__(256) void kA_prep(
    const float* __restrict__ ckvc, const float* __restrict__ kpec,
    const float* __restrict__ ckvn, const float* __restrict__ kpein,
    const float* __restrict__ cosc, const float* __restrict__ sinc,
    const int* __restrict__ sposp, int cap,
    unsigned short* __restrict__ kvbf, unsigned short* __restrict__ vT,
    const float* __restrict__ x, const float* __restrict__ wq,
    float* __restrict__ qfull) {
  __shared__ __align__(16) float smem[9216];  // 36,864 B shared by both paths
  const int bx = blockIdx.x;
  const int tid = threadIdx.x;

  if (bx < NTILE * 16) {
    // ---- k0: build bf16 KV in 2 layouts, zero-fill tail ----
    unsigned short* tile_sh = (unsigned short*)smem;  // [32][576]
    const int b = bx / NTILE;
    const int tile = bx - b * NTILE;
    const int n0 = tile * 32;
    const int spos = sposp[0];
#pragma unroll
    for (int i = 0; i < 18; ++i) {
      int u = tid + i * 256;
      int row = u / 144, c4 = (u - row * 144) * 4;
      int n = n0 + row;
      float4 v = make_float4(0.f, 0.f, 0.f, 0.f);
      if (n < spos) {
        if (c4 < 512) v = *(const float4*)(ckvc + ((size_t)b * cap + n) * 512 + c4);
        else          v = *(const float4*)(kpec + ((size_t)b * cap + n) * 64 + (c4 - 512));
      } else if (n == spos) {
        if (c4 < 512) v = *(const float4*)(ckvn + (size_t)b * 512 + c4);
        else {
          int d = c4 - 512;
          const float* kp = kpein + b * 64;
          float o[4];
          if (d < 32) {
#pragma unroll
            for (int k = 0; k < 4; ++k) {
              int j = d + k;
              o[k] = kp[2 * j] * cosc[spos * 64 + j] - kp[2 * j + 1] * sinc[spos * 64 + j];
            }
          } else {
#pragma unroll
            for (int k = 0; k < 4; ++k) {
              int j = d - 32 + k;
              o[k] = kp[2 * j + 1] * cosc[spos * 64 + j] + kp[2 * j] * sinc[spos * 64 + j];
            }
          }
          v = make_float4(o[0], o[1], o[2], o[3]);
        }
      }
      *(u16x4*)&tile_sh[row * 576 + c4] = cvt4(v);
    }
    __syncthreads();
    unsigned short* dst = kvbf + ((size_t)b * KVROWS + n0) * 576;
#pragma unroll
    for (int i = 0; i < 9; ++i) {
      int u = tid + i * 256;
      *(f32x4*)&dst[u * 8] = *(const f32x4*)&tile_sh[u * 8];
    }
    unsigned short* vdst = vT + ((size_t)b * NTILE + tile) * 16384;
#pragma unroll
    for (int i = 0; i < 16; ++i) {
      int u = tid + i * 256;
      int c = u & 511, ng = u >> 9;
      u16x4 w;
#pragma unroll
      for (int k = 0; k < 4; ++k) w[k] = tile_sh[(ng * 4 + k) * 576 + c];
      *(u16x4*)&vdst[c * 32 + ng * 4] = w;
    }
  } else {
    // ---- k1: q_full[b][n] = dot(x[b][:], wq[n][:]) ----
    float* xs = smem;  // [16][512]
    const int lane = tid & 63, wid = tid >> 6;
    const int row0 = (bx - NTILE * 16) * 16 + wid * 4;
    float acc[4][16];
#pragma unroll
    for (int r = 0; r < 4; ++r)
#pragma unroll
      for (int bb = 0; bb < 16; ++bb) acc[r][bb] = 0.f;

    for (int kt = 0; kt < 3; ++kt) {
      __syncthreads();
      for (int u = tid; u < 2048; u += 256) {
        int bb = u >> 7, k4 = (u & 127) << 2;
        *(float4*)&xs[bb * 512 + k4] = *(const float4*)&x[bb * 1536 + kt * 512 + k4];
      }
      __syncthreads();
#pragma unroll
      for (int it = 0; it < 2; ++it) {
        const int ko = it * 256 + lane * 4;
        float4 wv[4];
#pragma unroll
        for (int r = 0; r < 4; ++r)
          wv[r] = *(const float4*)&wq[(size_t)(row0 + r) * 1536 + kt * 512 + ko];
#pragma unroll
        for (int bb = 0; bb < 16; ++bb) {
          float4 xv = *(const float4*)&xs[bb * 512 + ko];
#pragma unroll
          for (int r = 0; r < 4; ++r)
            acc[r][bb] += wv[r].x * xv.x + wv[r].y * xv.y + wv[r].z * xv.z + wv[r].w * xv.w;
        }
      }
    }
#pragma unroll
    for (int r = 0; r < 4; ++r)
#pragma unroll
      for (int bb = 0; bb < 16; ++bb) {
        float v = acc[r][bb];
#pragma unroll
        for (int mk = 1; mk < 64; mk <<= 1) v += __shfl_xor(v, mk, 64);
        acc[r][bb] = v;
      }
#pragma unroll
    for (int r = 0; r < 4; ++r) {
      const int row = row0 + r;
#pragma unroll
      for (int bb = 0; bb < 16; ++bb)
        if (lane == bb) qfull[bb * 24576 + row] = acc[r][bb];
    }
  }
}

// ================= kB: fused k3 (absorb, blocks 0..255) || k2 (rope) ==========
__global__ __launch_bounds__(256) void kB_q(
    const float* __restrict__ qfull, const float* __restrict__ wkv,
    const float* __restrict__ cosc, const float* __restrict__ sinc,
    const int* __restrict__ sposp, unsigned short* __restrict__ qcat) {
  __shared__ float qs[16 * 128];
  const int bx = blockIdx.x;
  const int tid = threadIdx.x;
  if (bx < 256) {
    const int h = bx & 127;
    const int half = bx >> 7;
    for (int u = tid; u < 2048; u += 256) {
      int bb = u >> 7, d = u & 127;
      qs[u] = qfull[bb * 24576 + h * 192 + d];
    }
    __syncthreads();
    const int c = half * 256 + tid;
    float acc[16];
#pragma unroll
    for (int bb = 0; bb < 16; ++bb) acc[bb] = 0.f;
    const float* wbase = wkv + (size_t)h * 256 * 512;
    for (int d = 0; d < 128; ++d) {
      const float w = wbase[d * 512 + c];
#pragma unroll
      for (int bb = 0; bb < 16; ++bb) acc[bb] += qs[bb * 128 + d] * w;
    }
#pragma unroll
    for (int bb = 0; bb < 16; ++bb)
      qcat[(size_t)(bb * 128 + h) * 576 + c] = f2bf(acc[bb]);
  } else {
    const int b = bx - 256;
    const int pos = sposp[0];
#pragma unroll
    for (int i = 0; i < 16; ++i) {
      int idx = tid + i * 256;   // 0..4095
      int h = idx >> 5, j = idx & 31;
      const float cj = cosc[pos * 64 + j];
      const float sj = sinc[pos * 64 + j];
      const float* src = qfull + b * 24576 + h * 192 + 128;
      float x0 = src[2 * j], x1 = src[2 * j + 1];
      unsigned short* dst = qcat + (size_t)(b * 128 + h) * 576 + 512;
      dst[j] = f2bf(x0 * cj - x1 * sj);
      dst[j + 32] = f2bf(x1 * cj + x0 * sj);
    }
  }
}

// ================= k4: flash decode, 8 waves = 128 heads, dbuf gload_lds ======
// grid (NSPLIT, 16); block 512; 1 block/CU (149.5 KB LDS)
__global__ __launch_bounds__(512, 2) void k4_attn(
    const unsigned short* __restrict__ kvbf, const unsigned short* __restrict__ vT,
    const unsigned short* __restrict__ qcat, const int* __restrict__ sposp,
    unsigned short* __restrict__ opart, float* __restrict__ mlp) {
  __shared__ __align__(16) unsigned short kv_sh[2][32 * 576];  // linear; src pre-swz
  __shared__ __align__(16) unsigned short vt_sh[2][512 * 32];  // linear
  __shared__ __align__(16) unsigned short p_sh[8 * 640];       // wave-private

  const int tid = threadIdx.x;
  const int split = blockIdx.x, b = blockIdx.y;
  const int kvlen = sposp[0] + 1;
  const int lane = tid & 63, wid = tid >> 6;
  const int l15 = lane & 15, lg = lane >> 4;

  const unsigned short* kvb = kvbf + (size_t)b * KVROWS * 576;
  const unsigned short* vtb = vT + (size_t)b * NTILE * 16384;

  auto STAGE = [&](int pb, int tt) {
    const unsigned short* ksrc = kvb + (size_t)tt * 32 * 576;
    for (int j = wid; j < 36; j += 8) {           // 2304 kv chunks
      int u = j * 64 + lane;
      int row = u / 72, cc = u - row * 72;
      gload_lds16(ksrc + row * 576 + ((cc ^ (row & 7)) * 8), &kv_sh[pb][j * 512]);
    }
    const unsigned short* vsrc = vtb + (size_t)tt * 16384;
    for (int j = wid; j < 32; j += 8)             // 2048 vT chunks, linear
      gload_lds16(vsrc + j * 512 + lane * 8, &vt_sh[pb][j * 512]);
  };

  STAGE(0, split);

  // Q fragments in registers (16 heads per wave; 8 waves = 128 heads)
  const int hrow = b * 128 + wid * 16 + l15;
  const unsigned short* qrow = qcat + (size_t)hrow * 576;
  short8x qf[18];
#pragma unroll
  for (int s = 0; s < 18; ++s)
    qf[s] = *(const short8x*)(qrow + s * 32 + lg * 8);

  f32x4 acc[32];
#pragma unroll
  for (int i = 0; i < 32; ++i) acc[i] = (f32x4){0.f, 0.f, 0.f, 0.f};
  float mold[4] = {-1e30f, -1e30f, -1e30f, -1e30f};
  float lsum[4] = {0.f, 0.f, 0.f, 0.f};
  const float C2 = (1.0f / sqrtf(192.0f)) * 1.4426950408889634f;

  int pb = 0;
  for (int tt = split; tt * 32 < kvlen; tt += NSPLIT, pb ^= 1) {
    __syncthreads();   // drains this tile's async loads
    if ((tt + NSPLIT) * 32 < kvlen) STAGE(pb ^ 1, tt + NSPLIT);
    const int n0 = tt * 32;

    // QK^T : swizzled reads (LDS[n][c8] holds global chunk c8^(n&7))
    f32x4 D0 = (f32x4){0.f, 0.f, 0.f, 0.f};
    f32x4 D1 = (f32x4){0.f, 0.f, 0.f, 0.f};
#pragma unroll
    for (int s = 0; s < 18; ++s) {
      const int c8 = (s * 4 + lg) ^ (l15 & 7);
      short8x fb0 = *(const short8x*)&kv_sh[pb][l15 * 576 + c8 * 8];
      short8x fb1 = *(const short8x*)&kv_sh[pb][(16 + l15) * 576 + c8 * 8];
      D0 = __builtin_amdgcn_mfma_f32_16x16x32_bf16(qf[s], fb0, D0, 0, 0, 0);
      D1 = __builtin_amdgcn_mfma_f32_16x16x32_bf16(qf[s], fb1, D1, 0, 0, 0);
    }

    // online softmax (per-wave, 16 heads)
    const bool v0 = (n0 + l15) < kvlen;
    const bool v1 = (n0 + 16 + l15) < kvlen;
    float alpha[4];
#pragma unroll
    for (int r = 0; r < 4; ++r) {
      const float t0 = v0 ? D0[r] * C2 : -1e30f;
      const float t1 = v1 ? D1[r] * C2 : -1e30f;
      float mx = fmaxf(t0, t1);
      mx = fmaxf(mx, __shfl_xor(mx, 1, 64));
      mx = fmaxf(mx, __shfl_xor(mx, 2, 64));
      mx = fmaxf(mx, __shfl_xor(mx, 4, 64));
      mx = fmaxf(mx, __shfl_xor(mx, 8, 64));
      const float mn = fmaxf(mold[r], mx);
      alpha[r] = exp2f(mold[r] - mn);
      const float p0 = v0 ? exp2f(t0 - mn) : 0.f;
      const float p1 = v1 ? exp2f(t1 - mn) : 0.f;
      float rs = p0 + p1;
      rs += __shfl_xor(rs, 1, 64);
      rs += __shfl_xor(rs, 2, 64);
      rs += __shfl_xor(rs, 4, 64);
      rs += __shfl_xor(rs, 8, 64);
      lsum[r] = lsum[r] * alpha[r] + rs;
      mold[r] = mn;
      p_sh[wid * 640 + (lg * 4 + r) * 40 + l15] = f2bf(p0);
      p_sh[wid * 640 + (lg * 4 + r) * 40 + 16 + l15] = f2bf(p1);
    }
    const f32x4 av = {alpha[0], alpha[1], alpha[2], alpha[3]};
#pragma unroll
    for (int cg = 0; cg < 32; ++cg) acc[cg] *= av;

    // PV (wave-private p_sh; vt_sh staged at this tile's sync)
    const short8x pa = *(const short8x*)&p_sh[wid * 640 + l15 * 40 + lg * 8];
#pragma unroll
    for (int cg = 0; cg < 32; ++cg) {
      short8x bv = *(const short8x*)&vt_sh[pb][cg * 512 + l15 * 32 + lg * 8];
      acc[cg] = __builtin_amdgcn_mfma_f32_16x16x32_bf16(pa, bv, acc[cg], 0, 0, 0);
    }
  }

  // mlp partials (register layout: rows lg*4+r)
  const int hbm_ = b * 128 + wid * 16 + lg * 4;
  if (l15 == 0) {
#pragma unroll
    for (int r = 0; r < 4; ++r) {
      mlp[(size_t)(hbm_ + r) * (2 * NSPLIT) + split * 2] = mold[r];
      mlp[(size_t)(hbm_ + r) * (2 * NSPLIT) + split * 2 + 1] = lsum[r];
    }
  }

  // coalesced opart epilogue: transpose via now-free kv_sh (wave-private 8KB)
  __syncthreads();   // all waves done reading kv_sh
  unsigned short* ep = &kv_sh[0][0] + wid * 8192;   // [16 rows][512 c]
#pragma unroll
  for (int cg = 0; cg < 32; ++cg)
#pragma unroll
    for (int r = 0; r < 4; ++r)
      ep[(lg * 4 + r) * 512 + cg * 16 + l15] = f2bf(acc[cg][r]);
#pragma unroll
  for (int r16 = 0; r16 < 16; ++r16) {
    const int bh = b * 128 + wid * 16 + r16;
    const size_t ob = ((size_t)bh * NSPLIT + split) * 512;
#pragma unroll
    for (int i = 0; i < 2; ++i)
      *(u16x4*)&opart[ob + i * 256 + lane * 4] =
          *(const u16x4*)&ep[r16 * 512 + i * 256 + lane * 4];
  }
}

// ================= kC: fused combine + V-proj (one block per head) ============
__global__ __launch_bounds__(512) void kC_out(
    const unsigned short* __restrict__ opart, const float* __restrict__ mlp,
    const float* __restrict__ wkv, float* __restrict__ out) {
  __shared__ float os[16 * 512];
  __shared__ float wsc[16 * 16];
  __shared__ float lsc[16];
  const int h = blockIdx.x;
  const int tid = threadIdx.x;

  if (tid < 16) {
    const int b = tid;
    const float* m = mlp + (size_t)(b * 128 + h) * (2 * NSPLIT);
    float mi[NSPLIT], li[NSPLIT], M = -1e30f;
#pragma unroll
    for (int i = 0; i < NSPLIT; ++i) {
      mi[i] = m[i * 2];
      li[i] = m[i * 2 + 1];
      M = fmaxf(M, mi[i]);
    }
    float Ls = 0.f;
#pragma unroll
    for (int i = 0; i < NSPLIT; ++i) {
      const float w = exp2f(mi[i] - M);
      Ls += li[i] * w;
      wsc[b * NSPLIT + i] = w;
    }
    lsc[b] = Ls;
  }
  __syncthreads();

  for (int u = tid; u < 8192; u += 512) {
    const int b = u >> 9, c = u & 511;
    const unsigned short* op = opart + (size_t)(b * 128 + h) * NSPLIT * 512 + c;
    float o = 0.f;
#pragma unroll
    for (int i = 0; i < NSPLIT; ++i) o += wsc[b * NSPLIT + i] * bf2f(op[i * 512]);
    os[u] = o / lsc[b];
  }
  __syncthreads();

  const int d = tid >> 2, cq = tid & 3;
  const float* wrow = wkv + ((size_t)(h * 256 + 128 + d)) * 512;
  float acc[16];
#pragma unroll
  for (int bb = 0; bb < 16; ++bb) acc[bb] = 0.f;
  for (int i = 0; i < 32; ++i) {
    const int c = cq * 4 + i * 16;
    const float4 w4 = *(const float4*)&wrow[c];
#pragma unroll
    for (int bb = 0; bb < 16; ++bb) {
      const float4 o4 = *(const float4*)&os[bb * 512 + c];
      acc[bb] += w4.x * o4.x + w4.y * o4.y + w4.z * o4.z + w4.w * o4.w;
    }
  }
#pragma unroll
  for (int bb = 0; bb < 16; ++bb) {
    float v = acc[bb];
    v += __shfl_xor(v, 1, 64);
    v += __shfl_xor(v, 2, 64);
    if (cq == 0) out[(size_t)(bb * 128 + h) * 128 + d] = v;
  }
}

extern "C" void kernel_launch(void* const* d_in, const int* in_sizes, int n_in,
                              void* d_out, int out_size, void* d_ws, size_t ws_size,
                              hipStream_t stream) {
  const float* x = (const float*)d_in[0];
  const float* ckvn = (const float*)d_in[1];
  const float* kpein = (const float*)d_in[2];
  const int* sposp = (const int*)d_in[4];
  const float* ckvc = (const float*)d_in[5];
  const float* kpec = (const float*)d_in[6];
  const float* sinc = (const float*)d_in[7];
  const float* cosc = (const float*)d_in[8];
  const float* wkv = (const float*)d_in[9];
  const float* wq = (const float*)d_in[10];
  float* out = (float*)d_out;

  const int cap = in_sizes[5] / (16 * 512);

  float* ws = (float*)d_ws;
  float* qfull = ws;                                        // 393,216 f
  float* mlp = ws + 393216;                                 // 65,536 f
  unsigned short* qcat = (unsigned short*)(ws + 458752);    // 1,179,648 us
  unsigned short* kvbf = (unsigned short*)(ws + 1638400);   // 19,464,192 us
  unsigned short* vT   = (unsigned short*)(ws + 11370496);  // 17,301,504 us
  unsigned short* opart = (unsigned short*)(ws + 20021248); // 16,777,216 us
  // total 28,409,856 f = 113.6 MB

  kA_prep<<<dim3(NTILE * 16 + 1536), 256, 0, stream>>>(
      ckvc, kpec, ckvn, kpein, cosc, sinc, sposp, cap, kvbf, vT, x, wq, qfull);
  kB_q<<<dim3(272), 256, 0, stream>>>(qfull, wkv, cosc, sinc, sposp, qcat);
  k4_attn<<<dim3(NSPLIT, 16), 512, 0, stream>>>(kvbf, vT, qcat, sposp, opart, mlp);
  kC_out<<<dim3(128), 512, 0, stream>>>(opart, mlp, wkv, out);
}

// Round 6
// 208.352 us; speedup vs baseline: 1.5568x; 1.0023x over previous
//
#include <hip/hip_runtime.h>
#include <hip/hip_bf16.h>
#include <math.h>

typedef __attribute__((ext_vector_type(8))) short short8x;
typedef __attribute__((ext_vector_type(4))) float f32x4;
typedef __attribute__((ext_vector_type(4))) unsigned short u16x4;

#define NSPLIT 16
#define NTILE 66
#define KVROWS (NTILE * 32)

__device__ __forceinline__ unsigned short f2bf(float x) {
  unsigned int u = __float_as_uint(x);
  u += 0x7fffu + ((u >> 16) & 1u);   // RNE
  return (unsigned short)(u >> 16);
}
__device__ __forceinline__ float bf2f(unsigned short u) {
  return __uint_as_float(((unsigned int)u) << 16);
}
__device__ __forceinline__ u16x4 cvt4(float4 v) {
  u16x4 r;
  r[0] = f2bf(v.x); r[1] = f2bf(v.y); r[2] = f2bf(v.z); r[3] = f2bf(v.w);
  return r;
}
__device__ __forceinline__ void gload_lds16(const void* g, void* l) {
  __builtin_amdgcn_global_load_lds(
      (const __attribute__((address_space(1))) unsigned int*)g,
      (__attribute__((address_space(3))) unsigned int*)l, 16, 0, 0);
}

// ================= kP: KV-cache prep, no LDS ==================================
// partA (blocks 0..2375):   kvbf[b][n][576] bf16 stream-convert (zeros for n>spos)
// partB (blocks 2376..3431): vT[b][tile][c:512+64][n:32] from global, n>spos -> 0
__global__ __launch_bounds__(256) void kP_prep(
    const float* __restrict__ ckvc, const float* __restrict__ kpec,
    const float* __restrict__ ckvn, const float* __restrict__ kpein,
    const float* __restrict__ cosc, const float* __restrict__ sinc,
    const int* __restrict__ sposp, int cap,
    unsigned short* __restrict__ kvbf, unsigned short* __restrict__ vT) {
  const int bx = blockIdx.x;
  const int tid = threadIdx.x;
  const int spos = sposp[0];

  if (bx < 2376) {
    // ---- partA: row-major bf16 convert-copy (4-elem granules) ----
#pragma unroll
    for (int i = 0; i < 8; ++i) {
      const int u = bx * 2048 + i * 256 + tid;      // 4-elem chunk id
      const int b = u / 304128;
      const int r = u - b * 304128;
      const int n = r / 144;
      const int c4 = (r - n * 144) * 4;
      float4 v = make_float4(0.f, 0.f, 0.f, 0.f);
      if (n < spos) {
        if (c4 < 512) v = *(const float4*)(ckvc + ((size_t)b * cap + n) * 512 + c4);
        else          v = *(const float4*)(kpec + ((size_t)b * cap + n) * 64 + (c4 - 512));
      } else if (n == spos) {
        if (c4 < 512) v = *(const float4*)(ckvn + (size_t)b * 512 + c4);
        else {
          const int d = c4 - 512;
          const float* kp = kpein + b * 64;
          float o[4];
          if (d < 32) {
#pragma unroll
            for (int k = 0; k < 4; ++k) {
              int j = d + k;
              o[k] = kp[2 * j] * cosc[spos * 64 + j] - kp[2 * j + 1] * sinc[spos * 64 + j];
            }
          } else {
#pragma unroll
            for (int k = 0; k < 4; ++k) {
              int j = d - 32 + k;
              o[k] = kp[2 * j + 1] * cosc[spos * 64 + j] + kp[2 * j] * sinc[spos * 64 + j];
            }
          }
          v = make_float4(o[0], o[1], o[2], o[3]);
        }
      }
      *(u16x4*)(kvbf + (size_t)u * 4) = cvt4(v);   // FIX: u*4 (was u*8)
    }
  } else {
    // ---- partB: transposed V (and K-pe) tiles, [c][n] n-fast ----
    const int v_ = bx - 2376;
    const int b = v_ / NTILE;
    const int tile = v_ - b * NTILE;
    const int n0 = tile * 32;
    unsigned short* vdst = vT + ((size_t)b * NTILE + tile) * 18432;
    const bool fast = (n0 + 31) < spos;   // whole tile from caches
#pragma unroll 4
    for (int i = 0; i < 18; ++i) {
      const int o = i * 256 + tid;        // 4608 u16x4 chunks: c = o>>3, n4 = (o&7)*4
      const int c = o >> 3;
      const int n4 = (o & 7) * 4;
      float vv[4];
      if (fast) {
        if (c < 512) {
#pragma unroll
          for (int k = 0; k < 4; ++k) vv[k] = ckvc[((size_t)b * cap + n0 + n4 + k) * 512 + c];
        } else {
#pragma unroll
          for (int k = 0; k < 4; ++k) vv[k] = kpec[((size_t)b * cap + n0 + n4 + k) * 64 + (c - 512)];
        }
      } else {
#pragma unroll
        for (int k = 0; k < 4; ++k) {
          const int n = n0 + n4 + k;
          float x = 0.f;
          if (n < spos) {
            x = (c < 512) ? ckvc[((size_t)b * cap + n) * 512 + c]
                          : kpec[((size_t)b * cap + n) * 64 + (c - 512)];
          } else if (n == spos) {
            if (c < 512) x = ckvn[(size_t)b * 512 + c];
            else {
              const int d = c - 512;
              const float* kp = kpein + b * 64;
              const int j = (d < 32) ? d : d - 32;
              const float cj = cosc[spos * 64 + j], sj = sinc[spos * 64 + j];
              x = (d < 32) ? kp[2 * j] * cj - kp[2 * j + 1] * sj
                           : kp[2 * j + 1] * cj + kp[2 * j] * sj;
            }
          }
          vv[k] = x;
        }
      }
      u16x4 w;
#pragma unroll
      for (int k = 0; k < 4; ++k) w[k] = f2bf(vv[k]);
      *(u16x4*)(vdst + c * 32 + n4) = w;
    }
  }
}

// ================= k1: q_full = x * wq^T via global_load_lds dbuf =============
// grid 1536 blocks x 256 thr; 64 KB LDS; 2 blocks/CU
__global__ __launch_bounds__(256) void k1_qproj(const float* __restrict__ x,
                                                const float* __restrict__ wq,
                                                float* __restrict__ qfull) {
  __shared__ __align__(16) float wq_sh[2][4096];  // [16 rows][256 K]
  __shared__ __align__(16) float xs_sh[2][4096];  // [16 b][256 K]
  const int tid = threadIdx.x;
  const int lane = tid & 63, wid = tid >> 6;
  const int row0 = blockIdx.x * 16;

  auto STAGE = [&](int pb, int kt) {
#pragma unroll
    for (int i = 0; i < 4; ++i) {
      const int u = i * 256 + tid;        // 1024 chunks each
      const int row = u >> 6, k4 = (u & 63) * 4;
      gload_lds16(wq + (size_t)(row0 + row) * 1536 + kt * 256 + k4, &wq_sh[pb][u * 4]);
      gload_lds16(x + (size_t)row * 1536 + kt * 256 + k4, &xs_sh[pb][u * 4]);
    }
  };

  STAGE(0, 0);
  float acc[4][16];
#pragma unroll
  for (int r = 0; r < 4; ++r)
#pragma unroll
    for (int bb = 0; bb < 16; ++bb) acc[r][bb] = 0.f;

  int pb = 0;
  for (int kt = 0; kt < 6; ++kt, pb ^= 1) {
    __syncthreads();
    if (kt < 5) STAGE(pb ^ 1, kt + 1);
    const int ko = lane * 4;
    float4 wv[4];
#pragma unroll
    for (int r = 0; r < 4; ++r)
      wv[r] = *(const float4*)&wq_sh[pb][(wid * 4 + r) * 256 + ko];
#pragma unroll
    for (int bb = 0; bb < 16; ++bb) {
      const float4 xv = *(const float4*)&xs_sh[pb][bb * 256 + ko];
#pragma unroll
      for (int r = 0; r < 4; ++r)
        acc[r][bb] += wv[r].x * xv.x + wv[r].y * xv.y + wv[r].z * xv.z + wv[r].w * xv.w;
    }
  }
#pragma unroll
  for (int r = 0; r < 4; ++r)
#pragma unroll
    for (int bb = 0; bb < 16; ++bb) {
      float v = acc[r][bb];
#pragma unroll
      for (int mk = 1; mk < 64; mk <<= 1) v += __shfl_xor(v, mk, 64);
      acc[r][bb] = v;
    }
#pragma unroll
  for (int r = 0; r < 4; ++r) {
    const int row = row0 + wid * 4 + r;
#pragma unroll
    for (int bb = 0; bb < 16; ++bb)
      if (lane == bb) qfull[bb * 24576 + row] = acc[r][bb];
  }
}

// ================= kB: fused absorb (blocks 0..255) || rope (256..271) ========
__global__ __launch_bounds__(256) void kB_q(
    const float* __restrict__ qfull, const float* __restrict__ wkv,
    const float* __restrict__ cosc, const float* __restrict__ sinc,
    const int* __restrict__ sposp, unsigned short* __restrict__ qcat) {
  __shared__ float qs[16 * 128];
  const int bx = blockIdx.x;
  const int tid = threadIdx.x;
  if (bx < 256) {
    const int h = bx & 127;
    const int half = bx >> 7;
    for (int u = tid; u < 2048; u += 256) {
      int bb = u >> 7, d = u & 127;
      qs[u] = qfull[bb * 24576 + h * 192 + d];
    }
    __syncthreads();
    const int c = half * 256 + tid;
    float acc[16];
#pragma unroll
    for (int bb = 0; bb < 16; ++bb) acc[bb] = 0.f;
    const float* wbase = wkv + (size_t)h * 256 * 512;
    for (int d = 0; d < 128; ++d) {
      const float w = wbase[d * 512 + c];
#pragma unroll
      for (int bb = 0; bb < 16; ++bb) acc[bb] += qs[bb * 128 + d] * w;
    }
#pragma unroll
    for (int bb = 0; bb < 16; ++bb)
      qcat[(size_t)(bb * 128 + h) * 576 + c] = f2bf(acc[bb]);
  } else {
    const int b = bx - 256;
    const int pos = sposp[0];
#pragma unroll
    for (int i = 0; i < 16; ++i) {
      int idx = tid + i * 256;   // 0..4095
      int h = idx >> 5, j = idx & 31;
      const float cj = cosc[pos * 64 + j];
      const float sj = sinc[pos * 64 + j];
      const float* src = qfull + b * 24576 + h * 192 + 128;
      float x0 = src[2 * j], x1 = src[2 * j + 1];
      unsigned short* dst = qcat + (size_t)(b * 128 + h) * 576 + 512;
      dst[j] = f2bf(x0 * cj - x1 * sj);
      dst[j + 32] = f2bf(x1 * cj + x0 * sj);
    }
  }
}

// ================= k4: flash decode, 8 waves = 128 heads, dbuf gload_lds ======
__global__ __launch_bounds__(512, 2) void k4_attn(
    const unsigned short* __restrict__ kvbf, const unsigned short* __restrict__ vT,
    const unsigned short* __restrict__ qcat, const int* __restrict__ sposp,
    unsigned short* __restrict__ opart, float* __restrict__ mlp) {
  __shared__ __align__(16) unsigned short kv_sh[2][32 * 576];  // linear; src pre-swz
  __shared__ __align__(16) unsigned short vt_sh[2][512 * 32];  // linear
  __shared__ __align__(16) unsigned short p_sh[8 * 640];       // wave-private

  const int tid = threadIdx.x;
  const int split = blockIdx.x, b = blockIdx.y;
  const int kvlen = sposp[0] + 1;
  const int lane = tid & 63, wid = tid >> 6;
  const int l15 = lane & 15, lg = lane >> 4;

  const unsigned short* kvb = kvbf + (size_t)b * KVROWS * 576;
  const unsigned short* vtb = vT + (size_t)b * NTILE * 18432;

  auto STAGE = [&](int pb, int tt) {
    const unsigned short* ksrc = kvb + (size_t)tt * 32 * 576;
    for (int j = wid; j < 36; j += 8) {           // 2304 kv chunks
      int u = j * 64 + lane;
      int row = u / 72, cc = u - row * 72;
      gload_lds16(ksrc + row * 576 + ((cc ^ (row & 7)) * 8), &kv_sh[pb][j * 512]);
    }
    const unsigned short* vsrc = vtb + (size_t)tt * 18432;
    for (int j = wid; j < 32; j += 8)             // 2048 vT chunks, linear
      gload_lds16(vsrc + j * 512 + lane * 8, &vt_sh[pb][j * 512]);
  };

  STAGE(0, split);

  const int hrow = b * 128 + wid * 16 + l15;
  const unsigned short* qrow = qcat + (size_t)hrow * 576;
  short8x qf[18];
#pragma unroll
  for (int s = 0; s < 18; ++s)
    qf[s] = *(const short8x*)(qrow + s * 32 + lg * 8);

  f32x4 acc[32];
#pragma unroll
  for (int i = 0; i < 32; ++i) acc[i] = (f32x4){0.f, 0.f, 0.f, 0.f};
  float mold[4] = {-1e30f, -1e30f, -1e30f, -1e30f};
  float lsum[4] = {0.f, 0.f, 0.f, 0.f};
  const float C2 = (1.0f / sqrtf(192.0f)) * 1.4426950408889634f;

  int pb = 0;
  for (int tt = split; tt * 32 < kvlen; tt += NSPLIT, pb ^= 1) {
    __syncthreads();
    if ((tt + NSPLIT) * 32 < kvlen) STAGE(pb ^ 1, tt + NSPLIT);
    const int n0 = tt * 32;

    f32x4 D0 = (f32x4){0.f, 0.f, 0.f, 0.f};
    f32x4 D1 = (f32x4){0.f, 0.f, 0.f, 0.f};
#pragma unroll
    for (int s = 0; s < 18; ++s) {
      const int c8 = (s * 4 + lg) ^ (l15 & 7);
      short8x fb0 = *(const short8x*)&kv_sh[pb][l15 * 576 + c8 * 8];
      short8x fb1 = *(const short8x*)&kv_sh[pb][(16 + l15) * 576 + c8 * 8];
      D0 = __builtin_amdgcn_mfma_f32_16x16x32_bf16(qf[s], fb0, D0, 0, 0, 0);
      D1 = __builtin_amdgcn_mfma_f32_16x16x32_bf16(qf[s], fb1, D1, 0, 0, 0);
    }

    const bool v0 = (n0 + l15) < kvlen;
    const bool v1 = (n0 + 16 + l15) < kvlen;
    float alpha[4];
#pragma unroll
    for (int r = 0; r < 4; ++r) {
      const float t0 = v0 ? D0[r] * C2 : -1e30f;
      const float t1 = v1 ? D1[r] * C2 : -1e30f;
      float mx = fmaxf(t0, t1);
      mx = fmaxf(mx, __shfl_xor(mx, 1, 64));
      mx = fmaxf(mx, __shfl_xor(mx, 2, 64));
      mx = fmaxf(mx, __shfl_xor(mx, 4, 64));
      mx = fmaxf(mx, __shfl_xor(mx, 8, 64));
      const float mn = fmaxf(mold[r], mx);
      alpha[r] = exp2f(mold[r] - mn);
      const float p0 = v0 ? exp2f(t0 - mn) : 0.f;
      const float p1 = v1 ? exp2f(t1 - mn) : 0.f;
      float rs = p0 + p1;
      rs += __shfl_xor(rs, 1, 64);
      rs += __shfl_xor(rs, 2, 64);
      rs += __shfl_xor(rs, 4, 64);
      rs += __shfl_xor(rs, 8, 64);
      lsum[r] = lsum[r] * alpha[r] + rs;
      mold[r] = mn;
      p_sh[wid * 640 + (lg * 4 + r) * 40 + l15] = f2bf(p0);
      p_sh[wid * 640 + (lg * 4 + r) * 40 + 16 + l15] = f2bf(p1);
    }
    const f32x4 av = {alpha[0], alpha[1], alpha[2], alpha[3]};
#pragma unroll
    for (int cg = 0; cg < 32; ++cg) acc[cg] *= av;

    const short8x pa = *(const short8x*)&p_sh[wid * 640 + l15 * 40 + lg * 8];
#pragma unroll
    for (int cg = 0; cg < 32; ++cg) {
      short8x bv = *(const short8x*)&vt_sh[pb][cg * 512 + l15 * 32 + lg * 8];
      acc[cg] = __builtin_amdgcn_mfma_f32_16x16x32_bf16(pa, bv, acc[cg], 0, 0, 0);
    }
  }

  const int hbm_ = b * 128 + wid * 16 + lg * 4;
  if (l15 == 0) {
#pragma unroll
    for (int r = 0; r < 4; ++r) {
      mlp[(size_t)(hbm_ + r) * (2 * NSPLIT) + split * 2] = mold[r];
      mlp[(size_t)(hbm_ + r) * (2 * NSPLIT) + split * 2 + 1] = lsum[r];
    }
  }

  __syncthreads();
  unsigned short* ep = &kv_sh[0][0] + wid * 8192;   // [16 rows][512 c]
#pragma unroll
  for (int cg = 0; cg < 32; ++cg)
#pragma unroll
    for (int r = 0; r < 4; ++r)
      ep[(lg * 4 + r) * 512 + cg * 16 + l15] = f2bf(acc[cg][r]);
#pragma unroll
  for (int r16 = 0; r16 < 16; ++r16) {
    const int bh = b * 128 + wid * 16 + r16;
    const size_t ob = ((size_t)bh * NSPLIT + split) * 512;
#pragma unroll
    for (int i = 0; i < 2; ++i)
      *(u16x4*)&opart[ob + i * 256 + lane * 4] =
          *(const u16x4*)&ep[r16 * 512 + i * 256 + lane * 4];
  }
}

// ================= kC: fused combine + V-proj (one block per head) ============
__global__ __launch_bounds__(512) void kC_out(
    const unsigned short* __restrict__ opart, const float* __restrict__ mlp,
    const float* __restrict__ wkv, float* __restrict__ out) {
  __shared__ float os[16 * 512];
  __shared__ float wsc[16 * 16];
  __shared__ float lsc[16];
  const int h = blockIdx.x;
  const int tid = threadIdx.x;

  if (tid < 16) {
    const int b = tid;
    const float* m = mlp + (size_t)(b * 128 + h) * (2 * NSPLIT);
    float mi[NSPLIT], li[NSPLIT], M = -1e30f;
#pragma unroll
    for (int i = 0; i < NSPLIT; ++i) {
      mi[i] = m[i * 2];
      li[i] = m[i * 2 + 1];
      M = fmaxf(M, mi[i]);
    }
    float Ls = 0.f;
#pragma unroll
    for (int i = 0; i < NSPLIT; ++i) {
      const float w = exp2f(mi[i] - M);
      Ls += li[i] * w;
      wsc[b * NSPLIT + i] = w;
    }
    lsc[b] = Ls;
  }
  __syncthreads();

  for (int u = tid; u < 8192; u += 512) {
    const int b = u >> 9, c = u & 511;
    const unsigned short* op = opart + (size_t)(b * 128 + h) * NSPLIT * 512 + c;
    float o = 0.f;
#pragma unroll
    for (int i = 0; i < NSPLIT; ++i) o += wsc[b * NSPLIT + i] * bf2f(op[i * 512]);
    os[u] = o / lsc[b];
  }
  __syncthreads();

  const int d = tid >> 2, cq = tid & 3;
  const float* wrow = wkv + ((size_t)(h * 256 + 128 + d)) * 512;
  float acc[16];
#pragma unroll
  for (int bb = 0; bb < 16; ++bb) acc[bb] = 0.f;
  for (int i = 0; i < 32; ++i) {
    const int c = cq * 4 + i * 16;
    const float4 w4 = *(const float4*)&wrow[c];
#pragma unroll
    for (int bb = 0; bb < 16; ++bb) {
      const float4 o4 = *(const float4*)&os[bb * 512 + c];
      acc[bb] += w4.x * o4.x + w4.y * o4.y + w4.z * o4.z + w4.w * o4.w;
    }
  }
#pragma unroll
  for (int bb = 0; bb < 16; ++bb) {
    float v = acc[bb];
    v += __shfl_xor(v, 1, 64);
    v += __shfl_xor(v, 2, 64);
    if (cq == 0) out[(size_t)(bb * 128 + h) * 128 + d] = v;
  }
}

extern "C" void kernel_launch(void* const* d_in, const int* in_sizes, int n_in,
                              void* d_out, int out_size, void* d_ws, size_t ws_size,
                              hipStream_t stream) {
  const float* x = (const float*)d_in[0];
  const float* ckvn = (const float*)d_in[1];
  const float* kpein = (const float*)d_in[2];
  const int* sposp = (const int*)d_in[4];
  const float* ckvc = (const float*)d_in[5];
  const float* kpec = (const float*)d_in[6];
  const float* sinc = (const float*)d_in[7];
  const float* cosc = (const float*)d_in[8];
  const float* wkv = (const float*)d_in[9];
  const float* wq = (const float*)d_in[10];
  float* out = (float*)d_out;

  const int cap = in_sizes[5] / (16 * 512);

  float* ws = (float*)d_ws;
  float* qfull = ws;                                        // 393,216 f
  float* mlp = ws + 393216;                                 // 65,536 f
  unsigned short* qcat = (unsigned short*)(ws + 458752);    // 1,179,648 us
  unsigned short* kvbf = (unsigned short*)(ws + 1638400);   // 19,464,192 us
  unsigned short* vT   = (unsigned short*)(ws + 11370496);  // 16 * 66 * 18432 = 19,464,192 us
  unsigned short* opart = (unsigned short*)(ws + 21102592); // 16,777,216 us
  // total ~29.5 M floats = 118 MB

  kP_prep<<<dim3(3432), 256, 0, stream>>>(ckvc, kpec, ckvn, kpein, cosc, sinc,
                                          sposp, cap, kvbf, vT);
  k1_qproj<<<dim3(1536), 256, 0, stream>>>(x, wq, qfull);
  kB_q<<<dim3(272), 256, 0, stream>>>(qfull, wkv, cosc, sinc, sposp, qcat);
  k4_attn<<<dim3(NSPLIT, 16), 512, 0, stream>>>(kvbf, vT, qcat, sposp, opart, mlp);
  kC_out<<<dim3(128), 512, 0, stream>>>(opart, mlp, wkv, out);
}

// Round 7
// 191.086 us; speedup vs baseline: 1.6975x; 1.0904x over previous
//
#include <hip/hip_runtime.h>
#include <hip/hip_bf16.h>
#include <math.h>

typedef __attribute__((ext_vector_type(8))) short short8x;
typedef __attribute__((ext_vector_type(4))) float f32x4;
typedef __attribute__((ext_vector_type(4))) unsigned short u16x4;

#define NSPLIT 16
#define NTILE 66
#define KVROWS (NTILE * 32)

__device__ __forceinline__ unsigned short f2bf(float x) {
  unsigned int u = __float_as_uint(x);
  u += 0x7fffu + ((u >> 16) & 1u);   // RNE
  return (unsigned short)(u >> 16);
}
__device__ __forceinline__ float bf2f(unsigned short u) {
  return __uint_as_float(((unsigned int)u) << 16);
}
__device__ __forceinline__ u16x4 cvt4(float4 v) {
  u16x4 r;
  r[0] = f2bf(v.x); r[1] = f2bf(v.y); r[2] = f2bf(v.z); r[3] = f2bf(v.w);
  return r;
}
__device__ __forceinline__ void gload_lds16(const void* g, void* l) {
  __builtin_amdgcn_global_load_lds(
      (const __attribute__((address_space(1))) unsigned int*)g,
      (__attribute__((address_space(3))) unsigned int*)l, 16, 0, 0);
}

// ================= kP: KV-cache prep, no LDS ==================================
__global__ __launch_bounds__(256) void kP_prep(
    const float* __restrict__ ckvc, const float* __restrict__ kpec,
    const float* __restrict__ ckvn, const float* __restrict__ kpein,
    const float* __restrict__ cosc, const float* __restrict__ sinc,
    const int* __restrict__ sposp, int cap,
    unsigned short* __restrict__ kvbf, unsigned short* __restrict__ vT) {
  const int bx = blockIdx.x;
  const int tid = threadIdx.x;
  const int spos = sposp[0];

  if (bx < 2376) {
    // ---- partA: row-major bf16 convert-copy (4-elem granules) ----
#pragma unroll
    for (int i = 0; i < 8; ++i) {
      const int u = bx * 2048 + i * 256 + tid;      // 4-elem chunk id
      const int b = u / 304128;
      const int r = u - b * 304128;
      const int n = r / 144;
      const int c4 = (r - n * 144) * 4;
      float4 v = make_float4(0.f, 0.f, 0.f, 0.f);
      if (n < spos) {
        if (c4 < 512) v = *(const float4*)(ckvc + ((size_t)b * cap + n) * 512 + c4);
        else          v = *(const float4*)(kpec + ((size_t)b * cap + n) * 64 + (c4 - 512));
      } else if (n == spos) {
        if (c4 < 512) v = *(const float4*)(ckvn + (size_t)b * 512 + c4);
        else {
          const int d = c4 - 512;
          const float* kp = kpein + b * 64;
          float o[4];
          if (d < 32) {
#pragma unroll
            for (int k = 0; k < 4; ++k) {
              int j = d + k;
              o[k] = kp[2 * j] * cosc[spos * 64 + j] - kp[2 * j + 1] * sinc[spos * 64 + j];
            }
          } else {
#pragma unroll
            for (int k = 0; k < 4; ++k) {
              int j = d - 32 + k;
              o[k] = kp[2 * j + 1] * cosc[spos * 64 + j] + kp[2 * j] * sinc[spos * 64 + j];
            }
          }
          v = make_float4(o[0], o[1], o[2], o[3]);
        }
      }
      *(u16x4*)(kvbf + (size_t)u * 4) = cvt4(v);
    }
  } else {
    // ---- partB: transposed V (and K-pe) tiles, [c][n] n-fast ----
    const int v_ = bx - 2376;
    const int b = v_ / NTILE;
    const int tile = v_ - b * NTILE;
    const int n0 = tile * 32;
    unsigned short* vdst = vT + ((size_t)b * NTILE + tile) * 18432;
    const bool fast = (n0 + 31) < spos;
#pragma unroll 4
    for (int i = 0; i < 18; ++i) {
      const int o = i * 256 + tid;
      const int c = o >> 3;
      const int n4 = (o & 7) * 4;
      float vv[4];
      if (fast) {
        if (c < 512) {
#pragma unroll
          for (int k = 0; k < 4; ++k) vv[k] = ckvc[((size_t)b * cap + n0 + n4 + k) * 512 + c];
        } else {
#pragma unroll
          for (int k = 0; k < 4; ++k) vv[k] = kpec[((size_t)b * cap + n0 + n4 + k) * 64 + (c - 512)];
        }
      } else {
#pragma unroll
        for (int k = 0; k < 4; ++k) {
          const int n = n0 + n4 + k;
          float x = 0.f;
          if (n < spos) {
            x = (c < 512) ? ckvc[((size_t)b * cap + n) * 512 + c]
                          : kpec[((size_t)b * cap + n) * 64 + (c - 512)];
          } else if (n == spos) {
            if (c < 512) x = ckvn[(size_t)b * 512 + c];
            else {
              const int d = c - 512;
              const float* kp = kpein + b * 64;
              const int j = (d < 32) ? d : d - 32;
              const float cj = cosc[spos * 64 + j], sj = sinc[spos * 64 + j];
              x = (d < 32) ? kp[2 * j] * cj - kp[2 * j + 1] * sj
                           : kp[2 * j + 1] * cj + kp[2 * j] * sj;
            }
          }
          vv[k] = x;
        }
      }
      u16x4 w;
#pragma unroll
      for (int k = 0; k < 4; ++k) w[k] = f2bf(vv[k]);
      *(u16x4*)(vdst + c * 32 + n4) = w;
    }
  }
}

// ================= k1: q_full = x * wq^T ; wq->regs, x->LDS dbuf ==============
// grid 1536 x 256 thr; 32 KB LDS; 4 blocks/CU
__global__ __launch_bounds__(256, 4) void k1_qproj(const float* __restrict__ x,
                                                   const float* __restrict__ wq,
                                                   float* __restrict__ qfull) {
  __shared__ __align__(16) float xs_sh[2][4096];  // [16 b][256 K] fp32
  const int tid = threadIdx.x;
  const int lane = tid & 63, wid = tid >> 6;
  const int row0 = blockIdx.x * 16 + wid * 4;     // wave owns 4 rows

  auto XSTAGE = [&](int pb, int kt) {
#pragma unroll
    for (int i = 0; i < 4; ++i) {
      const int u = i * 256 + tid;                // 1024 x 16B chunks
      const int bb = u >> 6, k4 = (u & 63) * 4;
      gload_lds16(x + (size_t)bb * 1536 + kt * 256 + k4, &xs_sh[pb][u * 4]);
    }
  };

  XSTAGE(0, 0);
  const float* wrow = wq + (size_t)row0 * 1536 + lane * 4;
  float4 wv[2][4];
#pragma unroll
  for (int r = 0; r < 4; ++r)
    wv[0][r] = *(const float4*)(wrow + (size_t)r * 1536);

  float acc[4][16];
#pragma unroll
  for (int r = 0; r < 4; ++r)
#pragma unroll
    for (int bb = 0; bb < 16; ++bb) acc[r][bb] = 0.f;

#pragma unroll
  for (int kt = 0; kt < 6; ++kt) {
    const int pb = kt & 1;
    __syncthreads();                    // xs[pb] + wv[pb] complete
    if (kt < 5) {
      XSTAGE(pb ^ 1, kt + 1);           // async x for next phase
#pragma unroll
      for (int r = 0; r < 4; ++r)       // wq regs for next phase, fly over compute
        wv[pb ^ 1][r] = *(const float4*)(wrow + (size_t)r * 1536 + (kt + 1) * 256);
    }
#pragma unroll
    for (int bb = 0; bb < 16; ++bb) {
      const float4 xv = *(const float4*)&xs_sh[pb][bb * 256 + lane * 4];
#pragma unroll
      for (int r = 0; r < 4; ++r)
        acc[r][bb] += wv[pb][r].x * xv.x + wv[pb][r].y * xv.y +
                      wv[pb][r].z * xv.z + wv[pb][r].w * xv.w;
    }
  }

  // reduce-scatter butterfly: lane l ends with full sum of value idx l = r*16+bb
  float vals[64];
#pragma unroll
  for (int r = 0; r < 4; ++r)
#pragma unroll
    for (int bb = 0; bb < 16; ++bb) vals[r * 16 + bb] = acc[r][bb];
#pragma unroll
  for (int s = 0; s < 6; ++s) {
    const int m = 1 << s;
    const bool keep = (lane >> s) & 1;
#pragma unroll
    for (int k = 0; k < (32 >> s); ++k) {
      const float a = vals[2 * k], b = vals[2 * k + 1];
      const float send = keep ? a : b;
      const float recv = __shfl_xor(send, m, 64);
      vals[k] = (keep ? b : a) + recv;
    }
  }
  qfull[(lane & 15) * 24576 + row0 + (lane >> 4)] = vals[0];
}

// ================= kB: fused absorb (blocks 0..255) || rope (256..271) ========
__global__ __launch_bounds__(256) void kB_q(
    const float* __restrict__ qfull, const float* __restrict__ wkv,
    const float* __restrict__ cosc, const float* __restrict__ sinc,
    const int* __restrict__ sposp, unsigned short* __restrict__ qcat) {
  __shared__ float qs[16 * 128];
  const int bx = blockIdx.x;
  const int tid = threadIdx.x;
  if (bx < 256) {
    const int h = bx & 127;
    const int half = bx >> 7;
    for (int u = tid; u < 2048; u += 256) {
      int bb = u >> 7, d = u & 127;
      qs[u] = qfull[bb * 24576 + h * 192 + d];
    }
    __syncthreads();
    const int c = half * 256 + tid;
    float acc[16];
#pragma unroll
    for (int bb = 0; bb < 16; ++bb) acc[bb] = 0.f;
    const float* wbase = wkv + (size_t)h * 256 * 512;
    for (int d = 0; d < 128; ++d) {
      const float w = wbase[d * 512 + c];
#pragma unroll
      for (int bb = 0; bb < 16; ++bb) acc[bb] += qs[bb * 128 + d] * w;
    }
#pragma unroll
    for (int bb = 0; bb < 16; ++bb)
      qcat[(size_t)(bb * 128 + h) * 576 + c] = f2bf(acc[bb]);
  } else {
    const int b = bx - 256;
    const int pos = sposp[0];
#pragma unroll
    for (int i = 0; i < 16; ++i) {
      int idx = tid + i * 256;
      int h = idx >> 5, j = idx & 31;
      const float cj = cosc[pos * 64 + j];
      const float sj = sinc[pos * 64 + j];
      const float* src = qfull + b * 24576 + h * 192 + 128;
      float x0 = src[2 * j], x1 = src[2 * j + 1];
      unsigned short* dst = qcat + (size_t)(b * 128 + h) * 576 + 512;
      dst[j] = f2bf(x0 * cj - x1 * sj);
      dst[j + 32] = f2bf(x1 * cj + x0 * sj);
    }
  }
}

// ================= k4: flash decode, 8 waves = 128 heads, dbuf gload_lds ======
__global__ __launch_bounds__(512, 2) void k4_attn(
    const unsigned short* __restrict__ kvbf, const unsigned short* __restrict__ vT,
    const unsigned short* __restrict__ qcat, const int* __restrict__ sposp,
    unsigned short* __restrict__ opart, float* __restrict__ mlp) {
  __shared__ __align__(16) unsigned short kv_sh[2][32 * 576];
  __shared__ __align__(16) unsigned short vt_sh[2][512 * 32];
  __shared__ __align__(16) unsigned short p_sh[8 * 640];

  const int tid = threadIdx.x;
  const int split = blockIdx.x, b = blockIdx.y;
  const int kvlen = sposp[0] + 1;
  const int lane = tid & 63, wid = tid >> 6;
  const int l15 = lane & 15, lg = lane >> 4;

  const unsigned short* kvb = kvbf + (size_t)b * KVROWS * 576;
  const unsigned short* vtb = vT + (size_t)b * NTILE * 18432;

  auto STAGE = [&](int pb, int tt) {
    const unsigned short* ksrc = kvb + (size_t)tt * 32 * 576;
    for (int j = wid; j < 36; j += 8) {
      int u = j * 64 + lane;
      int row = u / 72, cc = u - row * 72;
      gload_lds16(ksrc + row * 576 + ((cc ^ (row & 7)) * 8), &kv_sh[pb][j * 512]);
    }
    const unsigned short* vsrc = vtb + (size_t)tt * 18432;
    for (int j = wid; j < 32; j += 8)
      gload_lds16(vsrc + j * 512 + lane * 8, &vt_sh[pb][j * 512]);
  };

  STAGE(0, split);

  const int hrow = b * 128 + wid * 16 + l15;
  const unsigned short* qrow = qcat + (size_t)hrow * 576;
  short8x qf[18];
#pragma unroll
  for (int s = 0; s < 18; ++s)
    qf[s] = *(const short8x*)(qrow + s * 32 + lg * 8);

  f32x4 acc[32];
#pragma unroll
  for (int i = 0; i < 32; ++i) acc[i] = (f32x4){0.f, 0.f, 0.f, 0.f};
  float mold[4] = {-1e30f, -1e30f, -1e30f, -1e30f};
  float lsum[4] = {0.f, 0.f, 0.f, 0.f};
  const float C2 = (1.0f / sqrtf(192.0f)) * 1.4426950408889634f;

  int pb = 0;
  for (int tt = split; tt * 32 < kvlen; tt += NSPLIT, pb ^= 1) {
    __syncthreads();
    if ((tt + NSPLIT) * 32 < kvlen) STAGE(pb ^ 1, tt + NSPLIT);
    const int n0 = tt * 32;

    f32x4 D0 = (f32x4){0.f, 0.f, 0.f, 0.f};
    f32x4 D1 = (f32x4){0.f, 0.f, 0.f, 0.f};
#pragma unroll
    for (int s = 0; s < 18; ++s) {
      const int c8 = (s * 4 + lg) ^ (l15 & 7);
      short8x fb0 = *(const short8x*)&kv_sh[pb][l15 * 576 + c8 * 8];
      short8x fb1 = *(const short8x*)&kv_sh[pb][(16 + l15) * 576 + c8 * 8];
      D0 = __builtin_amdgcn_mfma_f32_16x16x32_bf16(qf[s], fb0, D0, 0, 0, 0);
      D1 = __builtin_amdgcn_mfma_f32_16x16x32_bf16(qf[s], fb1, D1, 0, 0, 0);
    }

    const bool v0 = (n0 + l15) < kvlen;
    const bool v1 = (n0 + 16 + l15) < kvlen;
    float alpha[4];
#pragma unroll
    for (int r = 0; r < 4; ++r) {
      const float t0 = v0 ? D0[r] * C2 : -1e30f;
      const float t1 = v1 ? D1[r] * C2 : -1e30f;
      float mx = fmaxf(t0, t1);
      mx = fmaxf(mx, __shfl_xor(mx, 1, 64));
      mx = fmaxf(mx, __shfl_xor(mx, 2, 64));
      mx = fmaxf(mx, __shfl_xor(mx, 4, 64));
      mx = fmaxf(mx, __shfl_xor(mx, 8, 64));
      const float mn = fmaxf(mold[r], mx);
      alpha[r] = exp2f(mold[r] - mn);
      const float p0 = v0 ? exp2f(t0 - mn) : 0.f;
      const float p1 = v1 ? exp2f(t1 - mn) : 0.f;
      float rs = p0 + p1;
      rs += __shfl_xor(rs, 1, 64);
      rs += __shfl_xor(rs, 2, 64);
      rs += __shfl_xor(rs, 4, 64);
      rs += __shfl_xor(rs, 8, 64);
      lsum[r] = lsum[r] * alpha[r] + rs;
      mold[r] = mn;
      p_sh[wid * 640 + (lg * 4 + r) * 40 + l15] = f2bf(p0);
      p_sh[wid * 640 + (lg * 4 + r) * 40 + 16 + l15] = f2bf(p1);
    }
    const f32x4 av = {alpha[0], alpha[1], alpha[2], alpha[3]};
#pragma unroll
    for (int cg = 0; cg < 32; ++cg) acc[cg] *= av;

    const short8x pa = *(const short8x*)&p_sh[wid * 640 + l15 * 40 + lg * 8];
#pragma unroll
    for (int cg = 0; cg < 32; ++cg) {
      short8x bv = *(const short8x*)&vt_sh[pb][cg * 512 + l15 * 32 + lg * 8];
      acc[cg] = __builtin_amdgcn_mfma_f32_16x16x32_bf16(pa, bv, acc[cg], 0, 0, 0);
    }
  }

  const int hbm_ = b * 128 + wid * 16 + lg * 4;
  if (l15 == 0) {
#pragma unroll
    for (int r = 0; r < 4; ++r) {
      mlp[(size_t)(hbm_ + r) * (2 * NSPLIT) + split * 2] = mold[r];
      mlp[(size_t)(hbm_ + r) * (2 * NSPLIT) + split * 2 + 1] = lsum[r];
    }
  }

  __syncthreads();
  unsigned short* ep = &kv_sh[0][0] + wid * 8192;
#pragma unroll
  for (int cg = 0; cg < 32; ++cg)
#pragma unroll
    for (int r = 0; r < 4; ++r)
      ep[(lg * 4 + r) * 512 + cg * 16 + l15] = f2bf(acc[cg][r]);
#pragma unroll
  for (int r16 = 0; r16 < 16; ++r16) {
    const int bh = b * 128 + wid * 16 + r16;
    const size_t ob = ((size_t)bh * NSPLIT + split) * 512;
#pragma unroll
    for (int i = 0; i < 2; ++i)
      *(u16x4*)&opart[ob + i * 256 + lane * 4] =
          *(const u16x4*)&ep[r16 * 512 + i * 256 + lane * 4];
  }
}

// ================= kC: fused combine + V-proj (one block per head) ============
__global__ __launch_bounds__(512) void kC_out(
    const unsigned short* __restrict__ opart, const float* __restrict__ mlp,
    const float* __restrict__ wkv, float* __restrict__ out) {
  __shared__ float os[16 * 512];
  __shared__ float wsc[16 * 16];
  __shared__ float lsc[16];
  const int h = blockIdx.x;
  const int tid = threadIdx.x;

  if (tid < 16) {
    const int b = tid;
    const float* m = mlp + (size_t)(b * 128 + h) * (2 * NSPLIT);
    float mi[NSPLIT], li[NSPLIT], M = -1e30f;
#pragma unroll
    for (int i = 0; i < NSPLIT; ++i) {
      mi[i] = m[i * 2];
      li[i] = m[i * 2 + 1];
      M = fmaxf(M, mi[i]);
    }
    float Ls = 0.f;
#pragma unroll
    for (int i = 0; i < NSPLIT; ++i) {
      const float w = exp2f(mi[i] - M);
      Ls += li[i] * w;
      wsc[b * NSPLIT + i] = w;
    }
    lsc[b] = Ls;
  }
  __syncthreads();

  for (int u = tid; u < 8192; u += 512) {
    const int b = u >> 9, c = u & 511;
    const unsigned short* op = opart + (size_t)(b * 128 + h) * NSPLIT * 512 + c;
    float o = 0.f;
#pragma unroll
    for (int i = 0; i < NSPLIT; ++i) o += wsc[b * NSPLIT + i] * bf2f(op[i * 512]);
    os[u] = o / lsc[b];
  }
  __syncthreads();

  const int d = tid >> 2, cq = tid & 3;
  const float* wrow = wkv + ((size_t)(h * 256 + 128 + d)) * 512;
  float acc[16];
#pragma unroll
  for (int bb = 0; bb < 16; ++bb) acc[bb] = 0.f;
  for (int i = 0; i < 32; ++i) {
    const int c = cq * 4 + i * 16;
    const float4 w4 = *(const float4*)&wrow[c];
#pragma unroll
    for (int bb = 0; bb < 16; ++bb) {
      const float4 o4 = *(const float4*)&os[bb * 512 + c];
      acc[bb] += w4.x * o4.x + w4.y * o4.y + w4.z * o4.z + w4.w * o4.w;
    }
  }
#pragma unroll
  for (int bb = 0; bb < 16; ++bb) {
    float v = acc[bb];
    v += __shfl_xor(v, 1, 64);
    v += __shfl_xor(v, 2, 64);
    if (cq == 0) out[(size_t)(bb * 128 + h) * 128 + d] = v;
  }
}

extern "C" void kernel_launch(void* const* d_in, const int* in_sizes, int n_in,
                              void* d_out, int out_size, void* d_ws, size_t ws_size,
                              hipStream_t stream) {
  const float* x = (const float*)d_in[0];
  const float* ckvn = (const float*)d_in[1];
  const float* kpein = (const float*)d_in[2];
  const int* sposp = (const int*)d_in[4];
  const float* ckvc = (const float*)d_in[5];
  const float* kpec = (const float*)d_in[6];
  const float* sinc = (const float*)d_in[7];
  const float* cosc = (const float*)d_in[8];
  const float* wkv = (const float*)d_in[9];
  const float* wq = (const float*)d_in[10];
  float* out = (float*)d_out;

  const int cap = in_sizes[5] / (16 * 512);

  float* ws = (float*)d_ws;
  float* qfull = ws;                                        // 393,216 f
  float* mlp = ws + 393216;                                 // 65,536 f
  unsigned short* qcat = (unsigned short*)(ws + 458752);    // 1,179,648 us
  unsigned short* kvbf = (unsigned short*)(ws + 1638400);   // 19,464,192 us
  unsigned short* vT   = (unsigned short*)(ws + 11370496);  // 19,464,192 us
  unsigned short* opart = (unsigned short*)(ws + 21102592); // 16,777,216 us

  kP_prep<<<dim3(3432), 256, 0, stream>>>(ckvc, kpec, ckvn, kpein, cosc, sinc,
                                          sposp, cap, kvbf, vT);
  k1_qproj<<<dim3(1536), 256, 0, stream>>>(x, wq, qfull);
  kB_q<<<dim3(272), 256, 0, stream>>>(qfull, wkv, cosc, sinc, sposp, qcat);
  k4_attn<<<dim3(NSPLIT, 16), 512, 0, stream>>>(kvbf, vT, qcat, sposp, opart, mlp);
  kC_out<<<dim3(128), 512, 0, stream>>>(opart, mlp, wkv, out);
}

// Round 8
// 189.405 us; speedup vs baseline: 1.7125x; 1.0089x over previous
//
#include <hip/hip_runtime.h>
#include <hip/hip_bf16.h>
#include <math.h>

typedef __attribute__((ext_vector_type(8))) short short8x;
typedef __attribute__((ext_vector_type(4))) float f32x4;
typedef __attribute__((ext_vector_type(4))) unsigned short u16x4;

#define NSPLIT 16
#define NTILE 66
#define KVROWS (NTILE * 32)

__device__ __forceinline__ unsigned short f2bf(float x) {
  unsigned int u = __float_as_uint(x);
  u += 0x7fffu + ((u >> 16) & 1u);   // RNE
  return (unsigned short)(u >> 16);
}
__device__ __forceinline__ float bf2f(unsigned short u) {
  return __uint_as_float(((unsigned int)u) << 16);
}
__device__ __forceinline__ u16x4 cvt4(float4 v) {
  u16x4 r;
  r[0] = f2bf(v.x); r[1] = f2bf(v.y); r[2] = f2bf(v.z); r[3] = f2bf(v.w);
  return r;
}
__device__ __forceinline__ void gload_lds16(const void* g, void* l) {
  __builtin_amdgcn_global_load_lds(
      (const __attribute__((address_space(1))) unsigned int*)g,
      (__attribute__((address_space(3))) unsigned int*)l, 16, 0, 0);
}

// ================= kP: KV partA stream-convert (0..2375) + x hi/lo split (2376)
__global__ __launch_bounds__(256) void kP_prep(
    const float* __restrict__ ckvc, const float* __restrict__ kpec,
    const float* __restrict__ ckvn, const float* __restrict__ kpein,
    const float* __restrict__ cosc, const float* __restrict__ sinc,
    const int* __restrict__ sposp, int cap,
    unsigned short* __restrict__ kvbf,
    const float* __restrict__ x,
    unsigned short* __restrict__ xh, unsigned short* __restrict__ xl) {
  const int bx = blockIdx.x;
  const int tid = threadIdx.x;
  const int spos = sposp[0];

  if (bx < 2376) {
    // ---- partA: kvbf[b][n][576] bf16 (zeros beyond spos) ----
#pragma unroll
    for (int i = 0; i < 8; ++i) {
      const int u = bx * 2048 + i * 256 + tid;      // 4-elem chunk id
      const int b = u / 304128;
      const int r = u - b * 304128;
      const int n = r / 144;
      const int c4 = (r - n * 144) * 4;
      float4 v = make_float4(0.f, 0.f, 0.f, 0.f);
      if (n < spos) {
        if (c4 < 512) v = *(const float4*)(ckvc + ((size_t)b * cap + n) * 512 + c4);
        else          v = *(const float4*)(kpec + ((size_t)b * cap + n) * 64 + (c4 - 512));
      } else if (n == spos) {
        if (c4 < 512) v = *(const float4*)(ckvn + (size_t)b * 512 + c4);
        else {
          const int d = c4 - 512;
          const float* kp = kpein + b * 64;
          float o[4];
          if (d < 32) {
#pragma unroll
            for (int k = 0; k < 4; ++k) {
              int j = d + k;
              o[k] = kp[2 * j] * cosc[spos * 64 + j] - kp[2 * j + 1] * sinc[spos * 64 + j];
            }
          } else {
#pragma unroll
            for (int k = 0; k < 4; ++k) {
              int j = d - 32 + k;
              o[k] = kp[2 * j + 1] * cosc[spos * 64 + j] + kp[2 * j] * sinc[spos * 64 + j];
            }
          }
          v = make_float4(o[0], o[1], o[2], o[3]);
        }
      }
      *(u16x4*)(kvbf + (size_t)u * 4) = cvt4(v);
    }
  } else {
    // ---- x hi/lo split: xh/xl[16][1536] bf16 (hi=truncate, lo=exact residual)
#pragma unroll
    for (int i = 0; i < 24; ++i) {
      const int u = i * 256 + tid;                  // float4 chunk
      const float4 v = *(const float4*)(x + u * 4);
      const float vf[4] = {v.x, v.y, v.z, v.w};
      u16x4 h, l;
#pragma unroll
      for (int k = 0; k < 4; ++k) {
        const unsigned int uu = __float_as_uint(vf[k]);
        const unsigned int hb = uu & 0xffff0000u;
        h[k] = (unsigned short)(hb >> 16);
        l[k] = f2bf(vf[k] - __uint_as_float(hb));
      }
      *(u16x4*)(xh + u * 4) = h;
      *(u16x4*)(xl + u * 4) = l;
    }
  }
}

// ================= k1v: MFMA q-proj (blocks 0..383) || vT build (384..1439) ===
// k1: q_full = x * wq^T via bf16 hi/lo MFMA (fp32-accurate), LDS/barrier-free
// vT: [b][tile][c:576][n:32] transposed copy from bf16 kvbf (L3-hot)
__global__ __launch_bounds__(256) void k1v(
    const float* __restrict__ wq,
    const unsigned short* __restrict__ xh, const unsigned short* __restrict__ xl,
    float* __restrict__ qfull,
    const unsigned short* __restrict__ kvbf, unsigned short* __restrict__ vT) {
  const int bx = blockIdx.x;
  const int tid = threadIdx.x;

  if (bx < 384) {
    const int lane = tid & 63, wid = tid >> 6;
    const int l15 = lane & 15, lg = lane >> 4;
    const int rowb = bx * 64 + wid * 16;
    const float* wrow = wq + (size_t)(rowb + l15) * 1536 + lg * 8;
    const unsigned short* xhp = xh + l15 * 1536 + lg * 8;
    const unsigned short* xlp = xl + l15 * 1536 + lg * 8;

    f32x4 acc = (f32x4){0.f, 0.f, 0.f, 0.f};
#pragma unroll 8
    for (int kc = 0; kc < 48; ++kc) {
      const float4 wA = *(const float4*)(wrow + kc * 32);
      const float4 wB = *(const float4*)(wrow + kc * 32 + 4);
      const short8x bh = *(const short8x*)(xhp + kc * 32);
      const short8x bl = *(const short8x*)(xlp + kc * 32);
      const float wf[8] = {wA.x, wA.y, wA.z, wA.w, wB.x, wB.y, wB.z, wB.w};
      short8x ah, al;
#pragma unroll
      for (int e = 0; e < 8; ++e) {
        const unsigned int uu = __float_as_uint(wf[e]);
        const unsigned int hb = uu & 0xffff0000u;
        ah[e] = (short)(hb >> 16);
        al[e] = (short)f2bf(wf[e] - __uint_as_float(hb));
      }
      acc = __builtin_amdgcn_mfma_f32_16x16x32_bf16(ah, bh, acc, 0, 0, 0);
      acc = __builtin_amdgcn_mfma_f32_16x16x32_bf16(ah, bl, acc, 0, 0, 0);
      acc = __builtin_amdgcn_mfma_f32_16x16x32_bf16(al, bh, acc, 0, 0, 0);
    }
    // D: col(lane&15)=b, row=4*(lane>>4)+r
#pragma unroll
    for (int r = 0; r < 4; ++r)
      qfull[(size_t)l15 * 24576 + rowb + lg * 4 + r] = acc[r];
  } else {
    // ---- vT from bf16 kvbf (zero-padded; no conditionals) ----
    const int v_ = bx - 384;
    const int b = v_ / NTILE;
    const int tile = v_ - b * NTILE;
    const int n0 = tile * 32;
    const unsigned short* kvb = kvbf + (size_t)b * KVROWS * 576;
    unsigned short* vdst = vT + ((size_t)b * NTILE + tile) * 18432;
#pragma unroll 6
    for (int i = 0; i < 18; ++i) {
      const int o = i * 256 + tid;      // 4608 chunks: c=o>>3, n4=(o&7)*4
      const int c = o >> 3;
      const int n4 = (o & 7) * 4;
      u16x4 w;
#pragma unroll
      for (int k = 0; k < 4; ++k) w[k] = kvb[(size_t)(n0 + n4 + k) * 576 + c];
      *(u16x4*)(vdst + c * 32 + n4) = w;
    }
  }
}

// ================= kB: fused absorb (blocks 0..255) || rope (256..271) ========
__global__ __launch_bounds__(256) void kB_q(
    const float* __restrict__ qfull, const float* __restrict__ wkv,
    const float* __restrict__ cosc, const float* __restrict__ sinc,
    const int* __restrict__ sposp, unsigned short* __restrict__ qcat) {
  __shared__ float qs[16 * 128];
  const int bx = blockIdx.x;
  const int tid = threadIdx.x;
  if (bx < 256) {
    const int h = bx & 127;
    const int half = bx >> 7;
    for (int u = tid; u < 2048; u += 256) {
      int bb = u >> 7, d = u & 127;
      qs[u] = qfull[bb * 24576 + h * 192 + d];
    }
    __syncthreads();
    const int c = half * 256 + tid;
    float acc[16];
#pragma unroll
    for (int bb = 0; bb < 16; ++bb) acc[bb] = 0.f;
    const float* wbase = wkv + (size_t)h * 256 * 512;
    for (int d = 0; d < 128; ++d) {
      const float w = wbase[d * 512 + c];
#pragma unroll
      for (int bb = 0; bb < 16; ++bb) acc[bb] += qs[bb * 128 + d] * w;
    }
#pragma unroll
    for (int bb = 0; bb < 16; ++bb)
      qcat[(size_t)(bb * 128 + h) * 576 + c] = f2bf(acc[bb]);
  } else {
    const int b = bx - 256;
    const int pos = sposp[0];
#pragma unroll
    for (int i = 0; i < 16; ++i) {
      int idx = tid + i * 256;
      int h = idx >> 5, j = idx & 31;
      const float cj = cosc[pos * 64 + j];
      const float sj = sinc[pos * 64 + j];
      const float* src = qfull + b * 24576 + h * 192 + 128;
      float x0 = src[2 * j], x1 = src[2 * j + 1];
      unsigned short* dst = qcat + (size_t)(b * 128 + h) * 576 + 512;
      dst[j] = f2bf(x0 * cj - x1 * sj);
      dst[j + 32] = f2bf(x1 * cj + x0 * sj);
    }
  }
}

// ================= k4: flash decode, 8 waves = 128 heads, dbuf gload_lds ======
__global__ __launch_bounds__(512, 2) void k4_attn(
    const unsigned short* __restrict__ kvbf, const unsigned short* __restrict__ vT,
    const unsigned short* __restrict__ qcat, const int* __restrict__ sposp,
    unsigned short* __restrict__ opart, float* __restrict__ mlp) {
  __shared__ __align__(16) unsigned short kv_sh[2][32 * 576];
  __shared__ __align__(16) unsigned short vt_sh[2][512 * 32];
  __shared__ __align__(16) unsigned short p_sh[8 * 640];

  const int tid = threadIdx.x;
  const int split = blockIdx.x, b = blockIdx.y;
  const int kvlen = sposp[0] + 1;
  const int lane = tid & 63, wid = tid >> 6;
  const int l15 = lane & 15, lg = lane >> 4;

  const unsigned short* kvb = kvbf + (size_t)b * KVROWS * 576;
  const unsigned short* vtb = vT + (size_t)b * NTILE * 18432;

  auto STAGE = [&](int pb, int tt) {
    const unsigned short* ksrc = kvb + (size_t)tt * 32 * 576;
    for (int j = wid; j < 36; j += 8) {
      int u = j * 64 + lane;
      int row = u / 72, cc = u - row * 72;
      gload_lds16(ksrc + row * 576 + ((cc ^ (row & 7)) * 8), &kv_sh[pb][j * 512]);
    }
    const unsigned short* vsrc = vtb + (size_t)tt * 18432;
    for (int j = wid; j < 32; j += 8)
      gload_lds16(vsrc + j * 512 + lane * 8, &vt_sh[pb][j * 512]);
  };

  STAGE(0, split);

  const int hrow = b * 128 + wid * 16 + l15;
  const unsigned short* qrow = qcat + (size_t)hrow * 576;
  short8x qf[18];
#pragma unroll
  for (int s = 0; s < 18; ++s)
    qf[s] = *(const short8x*)(qrow + s * 32 + lg * 8);

  f32x4 acc[32];
#pragma unroll
  for (int i = 0; i < 32; ++i) acc[i] = (f32x4){0.f, 0.f, 0.f, 0.f};
  float mold[4] = {-1e30f, -1e30f, -1e30f, -1e30f};
  float lsum[4] = {0.f, 0.f, 0.f, 0.f};
  const float C2 = (1.0f / sqrtf(192.0f)) * 1.4426950408889634f;

  int pb = 0;
  for (int tt = split; tt * 32 < kvlen; tt += NSPLIT, pb ^= 1) {
    __syncthreads();
    if ((tt + NSPLIT) * 32 < kvlen) STAGE(pb ^ 1, tt + NSPLIT);
    const int n0 = tt * 32;

    f32x4 D0 = (f32x4){0.f, 0.f, 0.f, 0.f};
    f32x4 D1 = (f32x4){0.f, 0.f, 0.f, 0.f};
#pragma unroll
    for (int s = 0; s < 18; ++s) {
      const int c8 = (s * 4 + lg) ^ (l15 & 7);
      short8x fb0 = *(const short8x*)&kv_sh[pb][l15 * 576 + c8 * 8];
      short8x fb1 = *(const short8x*)&kv_sh[pb][(16 + l15) * 576 + c8 * 8];
      D0 = __builtin_amdgcn_mfma_f32_16x16x32_bf16(qf[s], fb0, D0, 0, 0, 0);
      D1 = __builtin_amdgcn_mfma_f32_16x16x32_bf16(qf[s], fb1, D1, 0, 0, 0);
    }

    const bool v0 = (n0 + l15) < kvlen;
    const bool v1 = (n0 + 16 + l15) < kvlen;
    float alpha[4];
#pragma unroll
    for (int r = 0; r < 4; ++r) {
      const float t0 = v0 ? D0[r] * C2 : -1e30f;
      const float t1 = v1 ? D1[r] * C2 : -1e30f;
      float mx = fmaxf(t0, t1);
      mx = fmaxf(mx, __shfl_xor(mx, 1, 64));
      mx = fmaxf(mx, __shfl_xor(mx, 2, 64));
      mx = fmaxf(mx, __shfl_xor(mx, 4, 64));
      mx = fmaxf(mx, __shfl_xor(mx, 8, 64));
      const float mn = fmaxf(mold[r], mx);
      alpha[r] = exp2f(mold[r] - mn);
      const float p0 = v0 ? exp2f(t0 - mn) : 0.f;
      const float p1 = v1 ? exp2f(t1 - mn) : 0.f;
      float rs = p0 + p1;
      rs += __shfl_xor(rs, 1, 64);
      rs += __shfl_xor(rs, 2, 64);
      rs += __shfl_xor(rs, 4, 64);
      rs += __shfl_xor(rs, 8, 64);
      lsum[r] = lsum[r] * alpha[r] + rs;
      mold[r] = mn;
      p_sh[wid * 640 + (lg * 4 + r) * 40 + l15] = f2bf(p0);
      p_sh[wid * 640 + (lg * 4 + r) * 40 + 16 + l15] = f2bf(p1);
    }
    const f32x4 av = {alpha[0], alpha[1], alpha[2], alpha[3]};
#pragma unroll
    for (int cg = 0; cg < 32; ++cg) acc[cg] *= av;

    const short8x pa = *(const short8x*)&p_sh[wid * 640 + l15 * 40 + lg * 8];
#pragma unroll
    for (int cg = 0; cg < 32; ++cg) {
      short8x bv = *(const short8x*)&vt_sh[pb][cg * 512 + l15 * 32 + lg * 8];
      acc[cg] = __builtin_amdgcn_mfma_f32_16x16x32_bf16(pa, bv, acc[cg], 0, 0, 0);
    }
  }

  const int hbm_ = b * 128 + wid * 16 + lg * 4;
  if (l15 == 0) {
#pragma unroll
    for (int r = 0; r < 4; ++r) {
      mlp[(size_t)(hbm_ + r) * (2 * NSPLIT) + split * 2] = mold[r];
      mlp[(size_t)(hbm_ + r) * (2 * NSPLIT) + split * 2 + 1] = lsum[r];
    }
  }

  __syncthreads();
  unsigned short* ep = &kv_sh[0][0] + wid * 8192;
#pragma unroll
  for (int cg = 0; cg < 32; ++cg)
#pragma unroll
    for (int r = 0; r < 4; ++r)
      ep[(lg * 4 + r) * 512 + cg * 16 + l15] = f2bf(acc[cg][r]);
#pragma unroll
  for (int r16 = 0; r16 < 16; ++r16) {
    const int bh = b * 128 + wid * 16 + r16;
    const size_t ob = ((size_t)bh * NSPLIT + split) * 512;
#pragma unroll
    for (int i = 0; i < 2; ++i)
      *(u16x4*)&opart[ob + i * 256 + lane * 4] =
          *(const u16x4*)&ep[r16 * 512 + i * 256 + lane * 4];
  }
}

// ================= kC: fused combine + V-proj (one block per head) ============
__global__ __launch_bounds__(512) void kC_out(
    const unsigned short* __restrict__ opart, const float* __restrict__ mlp,
    const float* __restrict__ wkv, float* __restrict__ out) {
  __shared__ float os[16 * 512];
  __shared__ float wsc[16 * 16];
  __shared__ float lsc[16];
  const int h = blockIdx.x;
  const int tid = threadIdx.x;

  if (tid < 16) {
    const int b = tid;
    const float* m = mlp + (size_t)(b * 128 + h) * (2 * NSPLIT);
    float mi[NSPLIT], li[NSPLIT], M = -1e30f;
#pragma unroll
    for (int i = 0; i < NSPLIT; ++i) {
      mi[i] = m[i * 2];
      li[i] = m[i * 2 + 1];
      M = fmaxf(M, mi[i]);
    }
    float Ls = 0.f;
#pragma unroll
    for (int i = 0; i < NSPLIT; ++i) {
      const float w = exp2f(mi[i] - M);
      Ls += li[i] * w;
      wsc[b * NSPLIT + i] = w;
    }
    lsc[b] = Ls;
  }
  __syncthreads();

  for (int u = tid; u < 8192; u += 512) {
    const int b = u >> 9, c = u & 511;
    const unsigned short* op = opart + (size_t)(b * 128 + h) * NSPLIT * 512 + c;
    float o = 0.f;
#pragma unroll
    for (int i = 0; i < NSPLIT; ++i) o += wsc[b * NSPLIT + i] * bf2f(op[i * 512]);
    os[u] = o / lsc[b];
  }
  __syncthreads();

  const int d = tid >> 2, cq = tid & 3;
  const float* wrow = wkv + ((size_t)(h * 256 + 128 + d)) * 512;
  float acc[16];
#pragma unroll
  for (int bb = 0; bb < 16; ++bb) acc[bb] = 0.f;
  for (int i = 0; i < 32; ++i) {
    const int c = cq * 4 + i * 16;
    const float4 w4 = *(const float4*)&wrow[c];
#pragma unroll
    for (int bb = 0; bb < 16; ++bb) {
      const float4 o4 = *(const float4*)&os[bb * 512 + c];
      acc[bb] += w4.x * o4.x + w4.y * o4.y + w4.z * o4.z + w4.w * o4.w;
    }
  }
#pragma unroll
  for (int bb = 0; bb < 16; ++bb) {
    float v = acc[bb];
    v += __shfl_xor(v, 1, 64);
    v += __shfl_xor(v, 2, 64);
    if (cq == 0) out[(size_t)(bb * 128 + h) * 128 + d] = v;
  }
}

extern "C" void kernel_launch(void* const* d_in, const int* in_sizes, int n_in,
                              void* d_out, int out_size, void* d_ws, size_t ws_size,
                              hipStream_t stream) {
  const float* x = (const float*)d_in[0];
  const float* ckvn = (const float*)d_in[1];
  const float* kpein = (const float*)d_in[2];
  const int* sposp = (const int*)d_in[4];
  const float* ckvc = (const float*)d_in[5];
  const float* kpec = (const float*)d_in[6];
  const float* sinc = (const float*)d_in[7];
  const float* cosc = (const float*)d_in[8];
  const float* wkv = (const float*)d_in[9];
  const float* wq = (const float*)d_in[10];
  float* out = (float*)d_out;

  const int cap = in_sizes[5] / (16 * 512);

  float* ws = (float*)d_ws;
  float* qfull = ws;                                        // 393,216 f
  float* mlp = ws + 393216;                                 // 65,536 f
  unsigned short* qcat = (unsigned short*)(ws + 458752);    // 1,179,648 u16
  unsigned short* xh   = (unsigned short*)(ws + 1048576);   // 24,576 u16
  unsigned short* xl   = (unsigned short*)(ws + 1060864);   // 24,576 u16
  unsigned short* kvbf = (unsigned short*)(ws + 1073152);   // 19,464,192 u16
  unsigned short* vT   = (unsigned short*)(ws + 10805248);  // 19,464,192 u16
  unsigned short* opart = (unsigned short*)(ws + 20537344); // 16,777,216 u16
  // total 28,925,952 f = 115.7 MB

  kP_prep<<<dim3(2377), 256, 0, stream>>>(ckvc, kpec, ckvn, kpein, cosc, sinc,
                                          sposp, cap, kvbf, x, xh, xl);
  k1v<<<dim3(1440), 256, 0, stream>>>(wq, xh, xl, qfull, kvbf, vT);
  kB_q<<<dim3(272), 256, 0, stream>>>(qfull, wkv, cosc, sinc, sposp, qcat);
  k4_attn<<<dim3(NSPLIT, 16), 512, 0, stream>>>(kvbf, vT, qcat, sposp, opart, mlp);
  kC_out<<<dim3(128), 512, 0, stream>>>(opart, mlp, wkv, out);
}

// Round 9
// 184.895 us; speedup vs baseline: 1.7543x; 1.0244x over previous
//
#include <hip/hip_runtime.h>
#include <hip/hip_bf16.h>
#include <math.h>

typedef __attribute__((ext_vector_type(8))) short short8x;
typedef __attribute__((ext_vector_type(4))) float f32x4;
typedef __attribute__((ext_vector_type(4))) unsigned short u16x4;
typedef __attribute__((ext_vector_type(8))) unsigned short u16x8;

#define NSPLIT 16
#define NTILE 66
#define KVROWS (NTILE * 32)

__device__ __forceinline__ unsigned short f2bf(float x) {
  unsigned int u = __float_as_uint(x);
  u += 0x7fffu + ((u >> 16) & 1u);   // RNE
  return (unsigned short)(u >> 16);
}
__device__ __forceinline__ float bf2f(unsigned short u) {
  return __uint_as_float(((unsigned int)u) << 16);
}
__device__ __forceinline__ u16x4 cvt4(float4 v) {
  u16x4 r;
  r[0] = f2bf(v.x); r[1] = f2bf(v.y); r[2] = f2bf(v.z); r[3] = f2bf(v.w);
  return r;
}
__device__ __forceinline__ void gload_lds16(const void* g, void* l) {
  __builtin_amdgcn_global_load_lds(
      (const __attribute__((address_space(1))) unsigned int*)g,
      (__attribute__((address_space(3))) unsigned int*)l, 16, 0, 0);
}

// ================= kP: KV partA stream-convert (0..2375) + x hi/lo split (2376)
__global__ __launch_bounds__(256) void kP_prep(
    const float* __restrict__ ckvc, const float* __restrict__ kpec,
    const float* __restrict__ ckvn, const float* __restrict__ kpein,
    const float* __restrict__ cosc, const float* __restrict__ sinc,
    const int* __restrict__ sposp, int cap,
    unsigned short* __restrict__ kvbf,
    const float* __restrict__ x,
    unsigned short* __restrict__ xh, unsigned short* __restrict__ xl) {
  const int bx = blockIdx.x;
  const int tid = threadIdx.x;
  const int spos = sposp[0];

  if (bx < 2376) {
#pragma unroll
    for (int i = 0; i < 8; ++i) {
      const int u = bx * 2048 + i * 256 + tid;      // 4-elem chunk id
      const int b = u / 304128;
      const int r = u - b * 304128;
      const int n = r / 144;
      const int c4 = (r - n * 144) * 4;
      float4 v = make_float4(0.f, 0.f, 0.f, 0.f);
      if (n < spos) {
        if (c4 < 512) v = *(const float4*)(ckvc + ((size_t)b * cap + n) * 512 + c4);
        else          v = *(const float4*)(kpec + ((size_t)b * cap + n) * 64 + (c4 - 512));
      } else if (n == spos) {
        if (c4 < 512) v = *(const float4*)(ckvn + (size_t)b * 512 + c4);
        else {
          const int d = c4 - 512;
          const float* kp = kpein + b * 64;
          float o[4];
          if (d < 32) {
#pragma unroll
            for (int k = 0; k < 4; ++k) {
              int j = d + k;
              o[k] = kp[2 * j] * cosc[spos * 64 + j] - kp[2 * j + 1] * sinc[spos * 64 + j];
            }
          } else {
#pragma unroll
            for (int k = 0; k < 4; ++k) {
              int j = d - 32 + k;
              o[k] = kp[2 * j + 1] * cosc[spos * 64 + j] + kp[2 * j] * sinc[spos * 64 + j];
            }
          }
          v = make_float4(o[0], o[1], o[2], o[3]);
        }
      }
      *(u16x4*)(kvbf + (size_t)u * 4) = cvt4(v);
    }
  } else {
    // x hi/lo split: xh/xl[16][1536] bf16 (hi=truncate, lo=exact residual)
#pragma unroll
    for (int i = 0; i < 24; ++i) {
      const int u = i * 256 + tid;
      const float4 v = *(const float4*)(x + u * 4);
      const float vf[4] = {v.x, v.y, v.z, v.w};
      u16x4 h, l;
#pragma unroll
      for (int k = 0; k < 4; ++k) {
        const unsigned int uu = __float_as_uint(vf[k]);
        const unsigned int hb = uu & 0xffff0000u;
        h[k] = (unsigned short)(hb >> 16);
        l[k] = f2bf(vf[k] - __uint_as_float(hb));
      }
      *(u16x4*)(xh + u * 4) = h;
      *(u16x4*)(xl + u * 4) = l;
    }
  }
}

// ================= kVT: vT[b][tile][c:576][n:32] via LDS-swizzled transpose ===
// 1056 blocks; reads bf16 kvbf coalesced (L3-hot), writes vT fully coalesced
__global__ __launch_bounds__(256) void kVT(
    const unsigned short* __restrict__ kvbf, unsigned short* __restrict__ vT) {
  __shared__ __align__(16) unsigned short tile_sh[32 * 576];
  const int v_ = blockIdx.x;
  const int b = v_ / NTILE;
  const int tile = v_ - b * NTILE;
  const int tid = threadIdx.x;
  const int wid = tid >> 6;
  const unsigned short* src = kvbf + ((size_t)b * KVROWS + tile * 32) * 576;

  // stage: LDS chunk (row,cc) holds global chunk (row, cc^(row&7))
#pragma unroll
  for (int i = 0; i < 9; ++i) {
    const int ch = i * 256 + tid;          // 16B chunk 0..2303
    const int row = ch / 72, cc = ch - row * 72;
    gload_lds16(src + row * 576 + ((cc ^ (row & 7)) * 8),
                &tile_sh[(i * 256 + wid * 64) * 8]);
  }
  __syncthreads();

  unsigned short* vdst = vT + ((size_t)b * NTILE + tile) * 18432;
#pragma unroll
  for (int r = 0; r < 9; ++r) {
    const int c = r * 64 + (tid >> 2);     // column 0..575
    const int q = tid & 3;                 // n-oct
    const int c8 = c >> 3, c7 = c & 7;
    u16x8 w;
#pragma unroll
    for (int j = 0; j < 8; ++j)            // element (n=q*8+j, c); n&7 == j
      w[j] = tile_sh[(q * 8 + j) * 576 + ((c8 ^ j) << 3) + c7];
    *(u16x8*)(vdst + c * 32 + q * 8) = w;  // wave-contiguous 1KB stores
  }
}

// ================= k1q: q_full = x * wq^T via bf16 hi/lo MFMA =================
// 384 blocks; LDS/barrier-free; wq streamed from HBM at full rate
__global__ __launch_bounds__(256) void k1q(
    const float* __restrict__ wq,
    const unsigned short* __restrict__ xh, const unsigned short* __restrict__ xl,
    float* __restrict__ qfull) {
  const int tid = threadIdx.x;
  const int lane = tid & 63, wid = tid >> 6;
  const int l15 = lane & 15, lg = lane >> 4;
  const int rowb = blockIdx.x * 64 + wid * 16;
  const float* wrow = wq + (size_t)(rowb + l15) * 1536 + lg * 8;
  const unsigned short* xhp = xh + l15 * 1536 + lg * 8;
  const unsigned short* xlp = xl + l15 * 1536 + lg * 8;

  f32x4 acc = (f32x4){0.f, 0.f, 0.f, 0.f};
#pragma unroll 8
  for (int kc = 0; kc < 48; ++kc) {
    const float4 wA = *(const float4*)(wrow + kc * 32);
    const float4 wB = *(const float4*)(wrow + kc * 32 + 4);
    const short8x bh = *(const short8x*)(xhp + kc * 32);
    const short8x bl = *(const short8x*)(xlp + kc * 32);
    const float wf[8] = {wA.x, wA.y, wA.z, wA.w, wB.x, wB.y, wB.z, wB.w};
    short8x ah, al;
#pragma unroll
    for (int e = 0; e < 8; ++e) {
      const unsigned int uu = __float_as_uint(wf[e]);
      const unsigned int hb = uu & 0xffff0000u;
      ah[e] = (short)(hb >> 16);
      al[e] = (short)f2bf(wf[e] - __uint_as_float(hb));
    }
    acc = __builtin_amdgcn_mfma_f32_16x16x32_bf16(ah, bh, acc, 0, 0, 0);
    acc = __builtin_amdgcn_mfma_f32_16x16x32_bf16(ah, bl, acc, 0, 0, 0);
    acc = __builtin_amdgcn_mfma_f32_16x16x32_bf16(al, bh, acc, 0, 0, 0);
  }
#pragma unroll
  for (int r = 0; r < 4; ++r)
    qfull[(size_t)l15 * 24576 + rowb + lg * 4 + r] = acc[r];
}

// ================= kB: fused absorb (blocks 0..255) || rope (256..271) ========
__global__ __launch_bounds__(256) void kB_q(
    const float* __restrict__ qfull, const float* __restrict__ wkv,
    const float* __restrict__ cosc, const float* __restrict__ sinc,
    const int* __restrict__ sposp, unsigned short* __restrict__ qcat) {
  __shared__ float qs[16 * 128];
  const int bx = blockIdx.x;
  const int tid = threadIdx.x;
  if (bx < 256) {
    const int h = bx & 127;
    const int half = bx >> 7;
    for (int u = tid; u < 2048; u += 256) {
      int bb = u >> 7, d = u & 127;
      qs[u] = qfull[bb * 24576 + h * 192 + d];
    }
    __syncthreads();
    const int c = half * 256 + tid;
    float acc[16];
#pragma unroll
    for (int bb = 0; bb < 16; ++bb) acc[bb] = 0.f;
    const float* wbase = wkv + (size_t)h * 256 * 512;
    for (int d = 0; d < 128; ++d) {
      const float w = wbase[d * 512 + c];
#pragma unroll
      for (int bb = 0; bb < 16; ++bb) acc[bb] += qs[bb * 128 + d] * w;
    }
#pragma unroll
    for (int bb = 0; bb < 16; ++bb)
      qcat[(size_t)(bb * 128 + h) * 576 + c] = f2bf(acc[bb]);
  } else {
    const int b = bx - 256;
    const int pos = sposp[0];
#pragma unroll
    for (int i = 0; i < 16; ++i) {
      int idx = tid + i * 256;
      int h = idx >> 5, j = idx & 31;
      const float cj = cosc[pos * 64 + j];
      const float sj = sinc[pos * 64 + j];
      const float* src = qfull + b * 24576 + h * 192 + 128;
      float x0 = src[2 * j], x1 = src[2 * j + 1];
      unsigned short* dst = qcat + (size_t)(b * 128 + h) * 576 + 512;
      dst[j] = f2bf(x0 * cj - x1 * sj);
      dst[j + 32] = f2bf(x1 * cj + x0 * sj);
    }
  }
}

// ================= k4: flash decode, 8 waves = 128 heads, dbuf gload_lds ======
__global__ __launch_bounds__(512, 2) void k4_attn(
    const unsigned short* __restrict__ kvbf, const unsigned short* __restrict__ vT,
    const unsigned short* __restrict__ qcat, const int* __restrict__ sposp,
    unsigned short* __restrict__ opart, float* __restrict__ mlp) {
  __shared__ __align__(16) unsigned short kv_sh[2][32 * 576];
  __shared__ __align__(16) unsigned short vt_sh[2][512 * 32];
  __shared__ __align__(16) unsigned short p_sh[8 * 640];

  const int tid = threadIdx.x;
  const int split = blockIdx.x, b = blockIdx.y;
  const int kvlen = sposp[0] + 1;
  const int lane = tid & 63, wid = tid >> 6;
  const int l15 = lane & 15, lg = lane >> 4;

  const unsigned short* kvb = kvbf + (size_t)b * KVROWS * 576;
  const unsigned short* vtb = vT + (size_t)b * NTILE * 18432;

  auto STAGE = [&](int pb, int tt) {
    const unsigned short* ksrc = kvb + (size_t)tt * 32 * 576;
    for (int j = wid; j < 36; j += 8) {
      int u = j * 64 + lane;
      int row = u / 72, cc = u - row * 72;
      gload_lds16(ksrc + row * 576 + ((cc ^ (row & 7)) * 8), &kv_sh[pb][j * 512]);
    }
    const unsigned short* vsrc = vtb + (size_t)tt * 18432;
    for (int j = wid; j < 32; j += 8)
      gload_lds16(vsrc + j * 512 + lane * 8, &vt_sh[pb][j * 512]);
  };

  STAGE(0, split);

  const int hrow = b * 128 + wid * 16 + l15;
  const unsigned short* qrow = qcat + (size_t)hrow * 576;
  short8x qf[18];
#pragma unroll
  for (int s = 0; s < 18; ++s)
    qf[s] = *(const short8x*)(qrow + s * 32 + lg * 8);

  f32x4 acc[32];
#pragma unroll
  for (int i = 0; i < 32; ++i) acc[i] = (f32x4){0.f, 0.f, 0.f, 0.f};
  float mold[4] = {-1e30f, -1e30f, -1e30f, -1e30f};
  float lsum[4] = {0.f, 0.f, 0.f, 0.f};
  const float C2 = (1.0f / sqrtf(192.0f)) * 1.4426950408889634f;

  int pb = 0;
  for (int tt = split; tt * 32 < kvlen; tt += NSPLIT, pb ^= 1) {
    __syncthreads();
    if ((tt + NSPLIT) * 32 < kvlen) STAGE(pb ^ 1, tt + NSPLIT);
    const int n0 = tt * 32;

    f32x4 D0 = (f32x4){0.f, 0.f, 0.f, 0.f};
    f32x4 D1 = (f32x4){0.f, 0.f, 0.f, 0.f};
#pragma unroll
    for (int s = 0; s < 18; ++s) {
      const int c8 = (s * 4 + lg) ^ (l15 & 7);
      short8x fb0 = *(const short8x*)&kv_sh[pb][l15 * 576 + c8 * 8];
      short8x fb1 = *(const short8x*)&kv_sh[pb][(16 + l15) * 576 + c8 * 8];
      D0 = __builtin_amdgcn_mfma_f32_16x16x32_bf16(qf[s], fb0, D0, 0, 0, 0);
      D1 = __builtin_amdgcn_mfma_f32_16x16x32_bf16(qf[s], fb1, D1, 0, 0, 0);
    }

    const bool v0 = (n0 + l15) < kvlen;
    const bool v1 = (n0 + 16 + l15) < kvlen;
    float alpha[4];
#pragma unroll
    for (int r = 0; r < 4; ++r) {
      const float t0 = v0 ? D0[r] * C2 : -1e30f;
      const float t1 = v1 ? D1[r] * C2 : -1e30f;
      float mx = fmaxf(t0, t1);
      mx = fmaxf(mx, __shfl_xor(mx, 1, 64));
      mx = fmaxf(mx, __shfl_xor(mx, 2, 64));
      mx = fmaxf(mx, __shfl_xor(mx, 4, 64));
      mx = fmaxf(mx, __shfl_xor(mx, 8, 64));
      const float mn = fmaxf(mold[r], mx);
      alpha[r] = exp2f(mold[r] - mn);
      const float p0 = v0 ? exp2f(t0 - mn) : 0.f;
      const float p1 = v1 ? exp2f(t1 - mn) : 0.f;
      float rs = p0 + p1;
      rs += __shfl_xor(rs, 1, 64);
      rs += __shfl_xor(rs, 2, 64);
      rs += __shfl_xor(rs, 4, 64);
      rs += __shfl_xor(rs, 8, 64);
      lsum[r] = lsum[r] * alpha[r] + rs;
      mold[r] = mn;
      p_sh[wid * 640 + (lg * 4 + r) * 40 + l15] = f2bf(p0);
      p_sh[wid * 640 + (lg * 4 + r) * 40 + 16 + l15] = f2bf(p1);
    }
    const f32x4 av = {alpha[0], alpha[1], alpha[2], alpha[3]};
#pragma unroll
    for (int cg = 0; cg < 32; ++cg) acc[cg] *= av;

    const short8x pa = *(const short8x*)&p_sh[wid * 640 + l15 * 40 + lg * 8];
#pragma unroll
    for (int cg = 0; cg < 32; ++cg) {
      short8x bv = *(const short8x*)&vt_sh[pb][cg * 512 + l15 * 32 + lg * 8];
      acc[cg] = __builtin_amdgcn_mfma_f32_16x16x32_bf16(pa, bv, acc[cg], 0, 0, 0);
    }
  }

  const int hbm_ = b * 128 + wid * 16 + lg * 4;
  if (l15 == 0) {
#pragma unroll
    for (int r = 0; r < 4; ++r) {
      mlp[(size_t)(hbm_ + r) * (2 * NSPLIT) + split * 2] = mold[r];
      mlp[(size_t)(hbm_ + r) * (2 * NSPLIT) + split * 2 + 1] = lsum[r];
    }
  }

  __syncthreads();
  unsigned short* ep = &kv_sh[0][0] + wid * 8192;
#pragma unroll
  for (int cg = 0; cg < 32; ++cg)
#pragma unroll
    for (int r = 0; r < 4; ++r)
      ep[(lg * 4 + r) * 512 + cg * 16 + l15] = f2bf(acc[cg][r]);
#pragma unroll
  for (int r16 = 0; r16 < 16; ++r16) {
    const int bh = b * 128 + wid * 16 + r16;
    const size_t ob = ((size_t)bh * NSPLIT + split) * 512;
#pragma unroll
    for (int i = 0; i < 2; ++i)
      *(u16x4*)&opart[ob + i * 256 + lane * 4] =
          *(const u16x4*)&ep[r16 * 512 + i * 256 + lane * 4];
  }
}

// ================= kC: fused combine + V-proj (one block per head) ============
__global__ __launch_bounds__(512) void kC_out(
    const unsigned short* __restrict__ opart, const float* __restrict__ mlp,
    const float* __restrict__ wkv, float* __restrict__ out) {
  __shared__ float os[16 * 512];
  __shared__ float wsc[16 * 16];
  __shared__ float lsc[16];
  const int h = blockIdx.x;
  const int tid = threadIdx.x;

  if (tid < 16) {
    const int b = tid;
    const float* m = mlp + (size_t)(b * 128 + h) * (2 * NSPLIT);
    float mi[NSPLIT], li[NSPLIT], M = -1e30f;
#pragma unroll
    for (int i = 0; i < NSPLIT; ++i) {
      mi[i] = m[i * 2];
      li[i] = m[i * 2 + 1];
      M = fmaxf(M, mi[i]);
    }
    float Ls = 0.f;
#pragma unroll
    for (int i = 0; i < NSPLIT; ++i) {
      const float w = exp2f(mi[i] - M);
      Ls += li[i] * w;
      wsc[b * NSPLIT + i] = w;
    }
    lsc[b] = Ls;
  }
  __syncthreads();

  for (int u = tid; u < 8192; u += 512) {
    const int b = u >> 9, c = u & 511;
    const unsigned short* op = opart + (size_t)(b * 128 + h) * NSPLIT * 512 + c;
    float o = 0.f;
#pragma unroll
    for (int i = 0; i < NSPLIT; ++i) o += wsc[b * NSPLIT + i] * bf2f(op[i * 512]);
    os[u] = o / lsc[b];
  }
  __syncthreads();

  const int d = tid >> 2, cq = tid & 3;
  const float* wrow = wkv + ((size_t)(h * 256 + 128 + d)) * 512;
  float acc[16];
#pragma unroll
  for (int bb = 0; bb < 16; ++bb) acc[bb] = 0.f;
  for (int i = 0; i < 32; ++i) {
    const int c = cq * 4 + i * 16;
    const float4 w4 = *(const float4*)&wrow[c];
#pragma unroll
    for (int bb = 0; bb < 16; ++bb) {
      const float4 o4 = *(const float4*)&os[bb * 512 + c];
      acc[bb] += w4.x * o4.x + w4.y * o4.y + w4.z * o4.z + w4.w * o4.w;
    }
  }
#pragma unroll
  for (int bb = 0; bb < 16; ++bb) {
    float v = acc[bb];
    v += __shfl_xor(v, 1, 64);
    v += __shfl_xor(v, 2, 64);
    if (cq == 0) out[(size_t)(bb * 128 + h) * 128 + d] = v;
  }
}

extern "C" void kernel_launch(void* const* d_in, const int* in_sizes, int n_in,
                              void* d_out, int out_size, void* d_ws, size_t ws_size,
                              hipStream_t stream) {
  const float* x = (const float*)d_in[0];
  const float* ckvn = (const float*)d_in[1];
  const float* kpein = (const float*)d_in[2];
  const int* sposp = (const int*)d_in[4];
  const float* ckvc = (const float*)d_in[5];
  const float* kpec = (const float*)d_in[6];
  const float* sinc = (const float*)d_in[7];
  const float* cosc = (const float*)d_in[8];
  const float* wkv = (const float*)d_in[9];
  const float* wq = (const float*)d_in[10];
  float* out = (float*)d_out;

  const int cap = in_sizes[5] / (16 * 512);

  float* ws = (float*)d_ws;
  float* qfull = ws;                                        // 393,216 f
  float* mlp = ws + 393216;                                 // 65,536 f
  unsigned short* qcat = (unsigned short*)(ws + 458752);    // 1,179,648 u16
  unsigned short* xh   = (unsigned short*)(ws + 1048576);   // 24,576 u16
  unsigned short* xl   = (unsigned short*)(ws + 1060864);   // 24,576 u16
  unsigned short* kvbf = (unsigned short*)(ws + 1073152);   // 19,464,192 u16
  unsigned short* vT   = (unsigned short*)(ws + 10805248);  // 19,464,192 u16
  unsigned short* opart = (unsigned short*)(ws + 20537344); // 16,777,216 u16

  kP_prep<<<dim3(2377), 256, 0, stream>>>(ckvc, kpec, ckvn, kpein, cosc, sinc,
                                          sposp, cap, kvbf, x, xh, xl);
  kVT<<<dim3(1056), 256, 0, stream>>>(kvbf, vT);
  k1q<<<dim3(384), 256, 0, stream>>>(wq, xh, xl, qfull);
  kB_q<<<dim3(272), 256, 0, stream>>>(qfull, wkv, cosc, sinc, sposp, qcat);
  k4_attn<<<dim3(NSPLIT, 16), 512, 0, stream>>>(kvbf, vT, qcat, sposp, opart, mlp);
  kC_out<<<dim3(128), 512, 0, stream>>>(opart, mlp, wkv, out);
}